// Round 9
// baseline (457.733 us; speedup 1.0000x reference)
//
#include <hip/hip_runtime.h>
#include <hip/hip_bf16.h>
#include <math.h>

#define NQ 9
#define NL 10
#define DIM 512
#define NCLS 10
#define B_TOT 16384

// ws layout (bytes): A bf16 [16384x512] @ 0 (16MB); BT bf16 [1024x512] @ 16MB (1MB);
// Zp f32 [8][16384][10] @ 32MB (5.25MB).  C is never materialized.
#define A_OFF   ((size_t)0)
#define BT_OFF  ((size_t)16 << 20)
#define ZP_OFF  ((size_t)32 << 20)
#define WS_NEED (((size_t)96) << 20)

__device__ __forceinline__ float shx(float v, int m) { return __shfl_xor(v, m, 64); }

__device__ __forceinline__ int looks_bf16(const void* p, int count) {
  const unsigned short* u = (const unsigned short*)p;
  int n = count < 64 ? count : 64;
  int good = 0;
  for (int i = 0; i < n; ++i) {
    unsigned short v = u[i];
    int e = (v >> 7) & 0xFF;
    good += (e >= 100 && e <= 140) || ((v & 0x7FFF) == 0);
  }
  return good * 8 >= n * 7;
}

__device__ __forceinline__ float ld(const void* p, int i, int isbf) {
  if (isbf) return __uint_as_float(((unsigned)((const unsigned short*)p)[i]) << 16);
  return ((const float*)p)[i];
}

// ---------------- 8-amp gate helpers (verified R3; used by fallback) -------
template<int M>
__device__ __forceinline__ void rot_x(float (&sr)[8], float (&si)[8], const float* u) {
  float4 uA = *(const float4*)u;
  float4 uB = *(const float4*)(u + 4);
  bool hi = (threadIdx.x & M) != 0;
  float ar = hi ? uB.z : uA.x, ai = hi ? uB.w : uA.y;
  float br = hi ? uB.x : uA.z, bi = hi ? uB.y : uA.w;
#pragma unroll
  for (int r = 0; r < 8; ++r) {
    float pr = shx(sr[r], M), pi = shx(si[r], M);
    float nr = ar * sr[r] - ai * si[r] + br * pr - bi * pi;
    float ni = ar * si[r] + ai * sr[r] + br * pi + bi * pr;
    sr[r] = nr; si[r] = ni;
  }
}
template<int S>
__device__ __forceinline__ void rot_r(float (&sr)[8], float (&si)[8], const float* u) {
  float4 uA = *(const float4*)u;
  float4 uB = *(const float4*)(u + 4);
#pragma unroll
  for (int r0 = 0; r0 < 8; ++r0) {
    if (r0 & S) continue;
    int r1 = r0 + S;
    float a0r = sr[r0], a0i = si[r0], a1r = sr[r1], a1i = si[r1];
    sr[r0] = uA.x * a0r - uA.y * a0i + uA.z * a1r - uA.w * a1i;
    si[r0] = uA.x * a0i + uA.y * a0r + uA.z * a1i + uA.w * a1r;
    sr[r1] = uB.x * a0r - uB.y * a0i + uB.z * a1r - uB.w * a1i;
    si[r1] = uB.x * a0i + uB.y * a0r + uB.z * a1i + uB.w * a1r;
  }
}
template<int MC, int MT>
__device__ __forceinline__ void crx_ll(float (&sr)[8], float (&si)[8], const float* cs) {
  bool ctrl = (threadIdx.x & MC) != 0;
  float c = ctrl ? cs[0] : 1.0f;
  float s = ctrl ? cs[1] : 0.0f;
#pragma unroll
  for (int r = 0; r < 8; ++r) {
    float pr = shx(sr[r], MT), pi = shx(si[r], MT);
    float nr = c * sr[r] + s * pi;
    float ni = c * si[r] - s * pr;
    sr[r] = nr; si[r] = ni;
  }
}
template<int MC, int ST>
__device__ __forceinline__ void crx_lr(float (&sr)[8], float (&si)[8], const float* cs) {
  bool ctrl = (threadIdx.x & MC) != 0;
  float c = ctrl ? cs[0] : 1.0f;
  float s = ctrl ? cs[1] : 0.0f;
#pragma unroll
  for (int r0 = 0; r0 < 8; ++r0) {
    if (r0 & ST) continue;
    int r1 = r0 + ST;
    float a0r = sr[r0], a0i = si[r0], a1r = sr[r1], a1i = si[r1];
    sr[r0] = c * a0r + s * a1i;  si[r0] = c * a0i - s * a1r;
    sr[r1] = c * a1r + s * a0i;  si[r1] = c * a1i - s * a0r;
  }
}
template<int PC, int ST>
__device__ __forceinline__ void crx_rr(float (&sr)[8], float (&si)[8], const float* cs) {
  float c = cs[0], s = cs[1];
#pragma unroll
  for (int r0 = 0; r0 < 8; ++r0) {
    if (r0 & ST) continue;
    if (!((r0 >> PC) & 1)) continue;
    int r1 = r0 + ST;
    float a0r = sr[r0], a0i = si[r0], a1r = sr[r1], a1i = si[r1];
    sr[r0] = c * a0r + s * a1i;  si[r0] = c * a0i - s * a1r;
    sr[r1] = c * a1r + s * a0i;  si[r1] = c * a1i - s * a0r;
  }
}
template<int PC, int MT>
__device__ __forceinline__ void crx_rl(float (&sr)[8], float (&si)[8], const float* cs) {
  float c = cs[0], s = cs[1];
#pragma unroll
  for (int r = 0; r < 8; ++r) {
    if (!((r >> PC) & 1)) continue;
    float pr = shx(sr[r], MT), pi = shx(si[r], MT);
    float nr = c * sr[r] + s * pi;
    float ni = c * si[r] - s * pr;
    sr[r] = nr; si[r] = ni;
  }
}

__device__ __forceinline__ void build_gates(const void* rot, const void* crx,
                                            float* gU, float* gCS) {
  int tid = threadIdx.x;
  __shared__ int gflags[2];
  if (tid == 0) {
    gflags[0] = looks_bf16(rot, NL * NQ * 3);
    gflags[1] = looks_bf16(crx, NL * NQ);
  }
  __syncthreads();
  if (tid < NL * NQ) {
    int frot = gflags[0], fcrx = gflags[1];
    float phi = ld(rot, tid * 3 + 0, frot);
    float th  = ld(rot, tid * 3 + 1, frot);
    float om  = ld(rot, tid * 3 + 2, frot);
    float c = cosf(0.5f * th), s = sinf(0.5f * th);
    float a = 0.5f * (phi + om), b = 0.5f * (phi - om);
    float ca = cosf(a), sa = sinf(a), cb = cosf(b), sb = sinf(b);
    float* u = gU + tid * 8;
    u[0] =  ca * c; u[1] = -sa * c;
    u[2] = -cb * s; u[3] = -sb * s;
    u[4] =  cb * s; u[5] = -sb * s;
    u[6] =  ca * c; u[7] =  sa * c;
    float t2 = 0.5f * ld(crx, tid, fcrx);
    gCS[tid * 2 + 0] = cosf(t2);
    gCS[tid * 2 + 1] = sinf(t2);
  }
  __syncthreads();
}

__device__ __forceinline__ void run_circuit(float (&sr)[8], float (&si)[8],
                                            const float* gU, const float* gCS) {
#pragma unroll 1
  for (int n = 0; n < NL; ++n) {
    const float* U  = gU  + n * NQ * 8;
    const float* CS = gCS + n * NQ * 2;
    rot_x<32>(sr, si, U + 0 * 8);
    rot_x<16>(sr, si, U + 1 * 8);
    rot_x< 8>(sr, si, U + 2 * 8);
    rot_x< 4>(sr, si, U + 3 * 8);
    rot_x< 2>(sr, si, U + 4 * 8);
    rot_x< 1>(sr, si, U + 5 * 8);
    rot_r< 4>(sr, si, U + 6 * 8);
    rot_r< 2>(sr, si, U + 7 * 8);
    rot_r< 1>(sr, si, U + 8 * 8);
    crx_ll<32, 16>(sr, si, CS + 0 * 2);
    crx_ll<16,  8>(sr, si, CS + 1 * 2);
    crx_ll< 8,  4>(sr, si, CS + 2 * 2);
    crx_ll< 4,  2>(sr, si, CS + 3 * 2);
    crx_ll< 2,  1>(sr, si, CS + 4 * 2);
    crx_lr< 1,  4>(sr, si, CS + 5 * 2);
    crx_rr< 2,  2>(sr, si, CS + 6 * 2);
    crx_rr< 1,  1>(sr, si, CS + 7 * 2);
    crx_rl< 0, 32>(sr, si, CS + 8 * 2);
  }
}

// ---------------- 2-amp gate helpers (4-wave-per-column wbuild) ------------
template<int M>
__device__ __forceinline__ void rot_lane2(float (&sr)[2], float (&si)[2], const float* u) {
  float4 uA = *(const float4*)u;
  float4 uB = *(const float4*)(u + 4);
  bool hi = (threadIdx.x & M) != 0;
  float ar = hi ? uB.z : uA.x, ai = hi ? uB.w : uA.y;
  float br = hi ? uB.x : uA.z, bi = hi ? uB.y : uA.w;
#pragma unroll
  for (int r = 0; r < 2; ++r) {
    float pr = shx(sr[r], M), pi = shx(si[r], M);
    float nr = ar * sr[r] - ai * si[r] + br * pr - bi * pi;
    float ni = ar * si[r] + ai * sr[r] + br * pi + bi * pr;
    sr[r] = nr; si[r] = ni;
  }
}
__device__ __forceinline__ void rot_reg2(float (&sr)[2], float (&si)[2], const float* u) {
  float4 uA = *(const float4*)u;
  float4 uB = *(const float4*)(u + 4);
  float a0r = sr[0], a0i = si[0], a1r = sr[1], a1i = si[1];
  sr[0] = uA.x * a0r - uA.y * a0i + uA.z * a1r - uA.w * a1i;
  si[0] = uA.x * a0i + uA.y * a0r + uA.z * a1i + uA.w * a1r;
  sr[1] = uB.x * a0r - uB.y * a0i + uB.z * a1r - uB.w * a1i;
  si[1] = uB.x * a0i + uB.y * a0r + uB.z * a1i + uB.w * a1r;
}
__device__ __forceinline__ void crx_lane2(float (&sr)[2], float (&si)[2],
                                          float c, float s, int MT) {
#pragma unroll
  for (int r = 0; r < 2; ++r) {
    float pr = shx(sr[r], MT), pi = shx(si[r], MT);
    float nr = c * sr[r] + s * pi;
    float ni = c * si[r] - s * pr;
    sr[r] = nr; si[r] = ni;
  }
}
__device__ __forceinline__ void crx_reg2(float (&sr)[2], float (&si)[2], float c, float s) {
  float a0r = sr[0], a0i = si[0], a1r = sr[1], a1i = si[1];
  sr[0] = c * a0r + s * a1i;  si[0] = c * a0i - s * a1r;
  sr[1] = c * a1r + s * a0i;  si[1] = c * a1i - s * a0r;
}

// -------- fused prep: blocks 0..511 build one W column each (4 waves/col),
// -------- blocks 512.. cast x->bf16 and fill remaining SIMDs ---------------
__global__ __launch_bounds__(256) void prep_kernel(const void* __restrict__ x,
                                                   const void* __restrict__ rot,
                                                   const void* __restrict__ crx,
                                                   __hip_bfloat16* __restrict__ A,
                                                   __hip_bfloat16* __restrict__ BT) {
  int tid = threadIdx.x;
  if (blockIdx.x < DIM) {
    __shared__ __align__(16) float gU[NL * NQ * 8];
    __shared__ __align__(16) float gCS[NL * NQ * 2];
    __shared__ float sRe[DIM], sIm[DIM];
    build_gates(rot, crx, gU, gCS);
    int lane = tid & 63, wv = tid >> 6;
    int idx0 = wv * 128 + lane * 2;
    int k = blockIdx.x;
    float sr[2], si[2];
    sr[0] = (idx0 == k) ? 1.f : 0.f;
    sr[1] = (idx0 + 1 == k) ? 1.f : 0.f;
    si[0] = si[1] = 0.f;
#pragma unroll 1
    for (int n = 0; n < NL; ++n) {
      const float* U  = gU  + n * NQ * 8;
      const float* CS = gCS + n * NQ * 2;
      __syncthreads();
      sRe[idx0] = sr[0]; sIm[idx0] = si[0];
      sRe[idx0 + 1] = sr[1]; sIm[idx0 + 1] = si[1];
      __syncthreads();
      {
        const float* U0 = U; const float* U1 = U + 8;
        int a = wv >> 1, b = wv & 1;
        float mr[4], mi[4];
#pragma unroll
        for (int w2 = 0; w2 < 4; ++w2) {
          int a2 = w2 >> 1, b2 = w2 & 1;
          float u0r = U0[(a * 2 + a2) * 2], u0i = U0[(a * 2 + a2) * 2 + 1];
          float u1r = U1[(b * 2 + b2) * 2], u1i = U1[(b * 2 + b2) * 2 + 1];
          mr[w2] = u0r * u1r - u0i * u1i;
          mi[w2] = u0r * u1i + u0i * u1r;
        }
#pragma unroll
        for (int r = 0; r < 2; ++r) {
          float nr = 0.f, ni = 0.f;
#pragma unroll
          for (int w2 = 0; w2 < 4; ++w2) {
            float xr = sRe[w2 * 128 + lane * 2 + r];
            float xi = sIm[w2 * 128 + lane * 2 + r];
            nr += mr[w2] * xr - mi[w2] * xi;
            ni += mr[w2] * xi + mi[w2] * xr;
          }
          sr[r] = nr; si[r] = ni;
        }
      }
      rot_lane2<32>(sr, si, U + 2 * 8);
      rot_lane2<16>(sr, si, U + 3 * 8);
      rot_lane2< 8>(sr, si, U + 4 * 8);
      rot_lane2< 4>(sr, si, U + 5 * 8);
      rot_lane2< 2>(sr, si, U + 6 * 8);
      rot_lane2< 1>(sr, si, U + 7 * 8);
      rot_reg2(sr, si, U + 8 * 8);
      __syncthreads();
      sRe[idx0] = sr[0]; sIm[idx0] = si[0];
      sRe[idx0 + 1] = sr[1]; sIm[idx0 + 1] = si[1];
      __syncthreads();
      {
        float c = (wv & 2) ? CS[0] : 1.f, s = (wv & 2) ? CS[1] : 0.f;
        int p0 = (wv ^ 1) * 128 + lane * 2;
#pragma unroll
        for (int r = 0; r < 2; ++r) {
          float pr = sRe[p0 + r], pi = sIm[p0 + r];
          float nr = c * sr[r] + s * pi;
          float ni = c * si[r] - s * pr;
          sr[r] = nr; si[r] = ni;
        }
      }
      { float c = (wv & 1) ? CS[2] : 1.f, s = (wv & 1) ? CS[3] : 0.f;
        crx_lane2(sr, si, c, s, 32); }
      { bool ct = (lane & 32); crx_lane2(sr, si, ct ? CS[4] : 1.f, ct ? CS[5] : 0.f, 16); }
      { bool ct = (lane & 16); crx_lane2(sr, si, ct ? CS[6] : 1.f, ct ? CS[7] : 0.f, 8); }
      { bool ct = (lane &  8); crx_lane2(sr, si, ct ? CS[8] : 1.f, ct ? CS[9] : 0.f, 4); }
      { bool ct = (lane &  4); crx_lane2(sr, si, ct ? CS[10] : 1.f, ct ? CS[11] : 0.f, 2); }
      { bool ct = (lane &  2); crx_lane2(sr, si, ct ? CS[12] : 1.f, ct ? CS[13] : 0.f, 1); }
      { bool ct = (lane & 1); crx_reg2(sr, si, ct ? CS[14] : 1.f, ct ? CS[15] : 0.f); }
      __syncthreads();
      sRe[idx0] = sr[0]; sIm[idx0] = si[0];
      sRe[idx0 + 1] = sr[1]; sIm[idx0 + 1] = si[1];
      __syncthreads();
      {
        float c = CS[16], s = CS[17];
        int p1 = (wv ^ 2) * 128 + lane * 2 + 1;
        float pr = sRe[p1], pi = sIm[p1];
        float nr = c * sr[1] + s * pi;
        float ni = c * si[1] - s * pr;
        sr[1] = nr; si[1] = ni;
      }
    }
#pragma unroll
    for (int r = 0; r < 2; ++r) {
      int j = idx0 + r;
      BT[(size_t)j * DIM + k]         = __float2bfloat16(sr[r]);  // Re W[j,k]
      BT[(size_t)(DIM + j) * DIM + k] = __float2bfloat16(si[r]);  // Im W[j,k]
    }
  } else {
    __shared__ int fx;
    if (tid == 0) fx = looks_bf16(x, B_TOT * DIM);
    __syncthreads();
    size_t i0 = ((size_t)(blockIdx.x - DIM) * 256 + tid) * 8;
    if (fx) {
      *(uint4*)(A + i0) = *(const uint4*)((const unsigned short*)x + i0);
    } else {
      const float4* src = (const float4*)((const float*)x + i0);
      float4 a = src[0], b = src[1];
      __hip_bfloat16 o[8];
      o[0] = __float2bfloat16(a.x); o[1] = __float2bfloat16(a.y);
      o[2] = __float2bfloat16(a.z); o[3] = __float2bfloat16(a.w);
      o[4] = __float2bfloat16(b.x); o[5] = __float2bfloat16(b.y);
      o[6] = __float2bfloat16(b.z); o[7] = __float2bfloat16(b.w);
      *(uint4*)(A + i0) = *(uint4*)o;
    }
  }
}

// ------- GEMM + fused z-reduction: Zp[panel][m][q] partials, no C ----------
// z_q(row) = sum_j sign_q(j) * |amp_j|^2, sign from bit (8-q) of j = col&511.
// Re and Im columns reduce independently (p = re^2 + im^2 splits).
using frag8 = __attribute__((ext_vector_type(8))) short;
using frag4 = __attribute__((ext_vector_type(4))) float;

typedef __attribute__((address_space(1))) const unsigned int GU32;
typedef __attribute__((address_space(3))) unsigned int LU32;
__device__ __forceinline__ void async16(const void* g, void* l) {
  __builtin_amdgcn_global_load_lds((GU32*)g, (LU32*)l, 16, 0, 0);
}

__global__ __launch_bounds__(256) void gemm_z_kernel(const unsigned short* __restrict__ A,
                                                     const unsigned short* __restrict__ BT,
                                                     float* __restrict__ Zp) {
  __shared__ __align__(16) unsigned short lsm[2 * 128 * 32];  // lA | lB, 16 KB
  unsigned short* lA = lsm;
  unsigned short* lB = lsm + 128 * 32;
  int bid = blockIdx.x;
  int xcd = bid & 7;
  int slot = bid >> 3;
  int n0 = (slot & 7) * 128;
  int m0 = (xcd * 16 + (slot >> 3)) * 128;
  int tid = threadIdx.x;
  int wv = tid >> 6, lane = tid & 63;
  int wm = wv >> 1, wn = wv & 1;
  int row = lane & 15, quad = lane >> 4;
  int srow = wv * 32 + (lane >> 2);
  int scol = (lane & 3) * 8;
  const unsigned short* gA = A + (size_t)(m0 + srow) * 512 + scol;
  const unsigned short* gB = BT + (size_t)(n0 + srow) * 512 + scol;
  frag4 acc[4][4] = {};
#pragma unroll 1
  for (int k0 = 0; k0 < 512; k0 += 32) {
    __syncthreads();
    async16(gA + k0,            &lA[(wv * 32) * 32]);
    async16(gA + k0 + 16 * 512, &lA[(wv * 32 + 16) * 32]);
    async16(gB + k0,            &lB[(wv * 32) * 32]);
    async16(gB + k0 + 16 * 512, &lB[(wv * 32 + 16) * 32]);
    __syncthreads();
    frag8 af[4], bf[4];
#pragma unroll
    for (int i = 0; i < 4; ++i) {
      af[i] = *(const frag8*)(&lA[(wm * 64 + i * 16 + row) * 32 + quad * 8]);
      bf[i] = *(const frag8*)(&lB[(wn * 64 + i * 16 + row) * 32 + quad * 8]);
    }
#pragma unroll
    for (int mi = 0; mi < 4; ++mi)
#pragma unroll
      for (int ni = 0; ni < 4; ++ni)
        acc[mi][ni] = __builtin_amdgcn_mfma_f32_16x16x32_bf16(af[mi], bf[ni],
                                                              acc[mi][ni], 0, 0, 0);
  }
  // ---- fused epilogue: acc tile -> z partials for 128 rows x 10 values ----
  // C/D layout: col = lane&15, row = quad*4 + reg   [verified R4-R8]
  float* zbuf = (float*)lsm;  // 2*128*10 floats = 10.2 KB, fits in 16 KB
  __syncthreads();            // all LDS frag reads done before reuse
  for (int i = tid; i < 2 * 128 * 10; i += 256) zbuf[i] = 0.f;
  __syncthreads();
  int colbase = n0 + wn * 64 + (lane & 15);
#pragma unroll 1
  for (int mi = 0; mi < 4; ++mi) {
    float zacc[4][10];
#pragma unroll
    for (int rg = 0; rg < 4; ++rg)
#pragma unroll
      for (int q = 0; q < 10; ++q) zacc[rg][q] = 0.f;
#pragma unroll
    for (int ni = 0; ni < 4; ++ni) {
      int j = (colbase + ni * 16) & 511;
      float sg[9];
#pragma unroll
      for (int q = 0; q < 9; ++q)
        sg[q] = ((j >> (8 - q)) & 1) ? -1.f : 1.f;
#pragma unroll
      for (int rg = 0; rg < 4; ++rg) {
        float v = acc[mi][ni][rg];
        float p = v * v;
#pragma unroll
        for (int q = 0; q < 9; ++q) zacc[rg][q] += sg[q] * p;
        zacc[rg][9] += p;
      }
    }
    // reduce over the 16 lanes of each quad (cols within this wave)
#pragma unroll
    for (int m = 1; m < 16; m <<= 1)
#pragma unroll
      for (int rg = 0; rg < 4; ++rg)
#pragma unroll
        for (int q = 0; q < 10; ++q) zacc[rg][q] += shx(zacc[rg][q], m);
    if ((lane & 15) == 0) {
      int rowl = wm * 64 + mi * 16 + quad * 4;
#pragma unroll
      for (int rg = 0; rg < 4; ++rg)
#pragma unroll
        for (int q = 0; q < 10; ++q)
          zbuf[(wn * 128 + rowl + rg) * 10 + q] = zacc[rg][q];
    }
  }
  __syncthreads();
  int panel = n0 >> 7;
  for (int i = tid; i < 128 * 10; i += 256) {
    int rowl = i / 10, q = i - rowl * 10;
    float v = zbuf[rowl * 10 + q] + zbuf[(128 + rowl) * 10 + q];
    Zp[(size_t)panel * (B_TOT * 10) + (size_t)(m0 + rowl) * 10 + q] = v;
  }
}

// ------- final reduction: sum 8 panels, normalize, logits, log_softmax -----
__global__ __launch_bounds__(256) void zred_kernel(const float* __restrict__ Zp,
                                                   const void* __restrict__ fcw,
                                                   const void* __restrict__ fcb,
                                                   float* __restrict__ out) {
  __shared__ int flags[2];
  __shared__ float sW[NCLS * NQ];
  __shared__ float sB[NCLS];
  int tid = threadIdx.x;
  if (tid == 0) {
    flags[0] = looks_bf16(fcw, NCLS * NQ);
    flags[1] = looks_bf16(fcb, NCLS);
  }
  __syncthreads();
  if (tid < NCLS * NQ) sW[tid] = ld(fcw, tid, flags[0]);
  if (tid < NCLS)      sB[tid] = ld(fcb, tid, flags[1]);
  __syncthreads();
  int row = blockIdx.x * 256 + tid;
  float z[10];
#pragma unroll
  for (int q = 0; q < 10; ++q) z[q] = 0.f;
#pragma unroll
  for (int pnl = 0; pnl < 8; ++pnl) {
    const float* p = Zp + (size_t)pnl * (B_TOT * 10) + (size_t)row * 10;
#pragma unroll
    for (int q = 0; q < 10; ++q) z[q] += p[q];
  }
  float invP = 1.0f / z[9];
#pragma unroll
  for (int q = 0; q < NQ; ++q) z[q] *= invP;
  float lg[NCLS], mx = -1e30f;
#pragma unroll
  for (int k = 0; k < NCLS; ++k) {
    float t = sB[k];
#pragma unroll
    for (int q = 0; q < NQ; ++q) t += z[q] * sW[k * NQ + q];
    lg[k] = t; mx = fmaxf(mx, t);
  }
  float se = 0.f;
#pragma unroll
  for (int k = 0; k < NCLS; ++k) se += expf(lg[k] - mx);
  float lse = mx + logf(se);
#pragma unroll
  for (int k = 0; k < NCLS; ++k) out[(size_t)row * NCLS + k] = lg[k] - lse;
}

// ---------------- fallback: round-3 passing monolithic kernel --------------
__global__ __launch_bounds__(256) void qnn_kernel(
    const void* __restrict__ x, const void* __restrict__ rot,
    const void* __restrict__ crx, const void* __restrict__ fcw,
    const void* __restrict__ fcb, float* __restrict__ out) {
  __shared__ __align__(16) float gU[NL * NQ * 8];
  __shared__ __align__(16) float gCS[NL * NQ * 2];
  __shared__ int flags[3];
  int tid = threadIdx.x;
  if (tid == 0) {
    flags[0] = looks_bf16(x, B_TOT * DIM);
    flags[1] = looks_bf16(fcw, NCLS * NQ);
    flags[2] = looks_bf16(fcb, NCLS);
  }
  build_gates(rot, crx, gU, gCS);
  __syncthreads();
  int wid = (blockIdx.x * blockDim.x + tid) >> 6;
  int lane = tid & 63;
  float sr[8], si[8];
  if (flags[0]) {
    const uint4 u = *(const uint4*)((const unsigned short*)x + (size_t)wid * DIM + lane * 8);
    sr[0] = __uint_as_float(u.x << 16); sr[1] = __uint_as_float(u.x & 0xffff0000u);
    sr[2] = __uint_as_float(u.y << 16); sr[3] = __uint_as_float(u.y & 0xffff0000u);
    sr[4] = __uint_as_float(u.z << 16); sr[5] = __uint_as_float(u.z & 0xffff0000u);
    sr[6] = __uint_as_float(u.w << 16); sr[7] = __uint_as_float(u.w & 0xffff0000u);
  } else {
    const float4* xf = (const float4*)((const float*)x + (size_t)wid * DIM) + lane * 2;
    float4 a = xf[0], b = xf[1];
    sr[0] = a.x; sr[1] = a.y; sr[2] = a.z; sr[3] = a.w;
    sr[4] = b.x; sr[5] = b.y; sr[6] = b.z; sr[7] = b.w;
  }
  float nrm = 0.f;
#pragma unroll
  for (int r = 0; r < 8; ++r) { nrm += sr[r] * sr[r]; si[r] = 0.f; }
#pragma unroll
  for (int m = 1; m < 64; m <<= 1) nrm += shx(nrm, m);
  float inv = rsqrtf(nrm);
  inv = inv * (1.5f - 0.5f * nrm * inv * inv);
#pragma unroll
  for (int r = 0; r < 8; ++r) sr[r] *= inv;
  run_circuit(sr, si, gU, gCS);
  float p[8], P = 0.f;
#pragma unroll
  for (int r = 0; r < 8; ++r) { p[r] = sr[r] * sr[r] + si[r] * si[r]; P += p[r]; }
  float z[NQ];
#pragma unroll
  for (int q = 0; q < 6; ++q) z[q] = (lane & (32 >> q)) ? -P : P;
  z[6] = z[7] = z[8] = 0.f;
#pragma unroll
  for (int r = 0; r < 8; ++r) {
    z[6] += (r & 4) ? -p[r] : p[r];
    z[7] += (r & 2) ? -p[r] : p[r];
    z[8] += (r & 1) ? -p[r] : p[r];
  }
#pragma unroll
  for (int m = 1; m < 64; m <<= 1) {
#pragma unroll
    for (int q = 0; q < NQ; ++q) z[q] += shx(z[q], m);
  }
  int ffw = flags[1], ffb = flags[2];
  float lg[NCLS], mx = -1e30f;
#pragma unroll
  for (int k = 0; k < NCLS; ++k) {
    float t = ld(fcb, k, ffb);
#pragma unroll
    for (int q = 0; q < NQ; ++q) t += z[q] * ld(fcw, k * NQ + q, ffw);
    lg[k] = t; mx = fmaxf(mx, t);
  }
  float se = 0.f;
#pragma unroll
  for (int k = 0; k < NCLS; ++k) se += expf(lg[k] - mx);
  float lse = mx + logf(se);
  if (lane < NCLS) out[(size_t)wid * NCLS + lane] = lg[lane] - lse;
}

extern "C" void kernel_launch(void* const* d_in, const int* in_sizes, int n_in,
                              void* d_out, int out_size, void* d_ws, size_t ws_size,
                              hipStream_t stream) {
  const void* x   = d_in[0];
  const void* rot = d_in[1];
  const void* crx = d_in[2];
  const void* fcw = d_in[3];
  const void* fcb = d_in[4];
  float* out = (float*)d_out;
  if (ws_size >= WS_NEED) {
    __hip_bfloat16* A  = (__hip_bfloat16*)((char*)d_ws + A_OFF);
    __hip_bfloat16* BT = (__hip_bfloat16*)((char*)d_ws + BT_OFF);
    float*          Zp = (float*)((char*)d_ws + ZP_OFF);
    prep_kernel<<<DIM + (B_TOT * DIM) / (256 * 8), 256, 0, stream>>>(x, rot, crx, A, BT);
    gemm_z_kernel<<<(B_TOT / 128) * (1024 / 128), 256, 0, stream>>>(
        (const unsigned short*)A, (const unsigned short*)BT, Zp);
    zred_kernel<<<B_TOT / 256, 256, 0, stream>>>(Zp, fcw, fcb, out);
  } else {
    qnn_kernel<<<(B_TOT * 64) / 256, 256, 0, stream>>>(x, rot, crx, fcw, fcb, out);
  }
}

// Round 10
// 173.172 us; speedup vs baseline: 2.6432x; 2.6432x over previous
//
#include <hip/hip_runtime.h>
#include <hip/hip_bf16.h>
#include <math.h>

#define NQ 9
#define NL 10
#define DIM 512
#define NCLS 10
#define B_TOT 16384

// ws layout (bytes): A bf16 [16384x512] @ 0 (16MB); BT bf16 [1024x512] @ 16MB (1MB);
// Zp f32 [8][16384][10] @ 32MB (5.25MB).  C is never materialized.
#define A_OFF   ((size_t)0)
#define BT_OFF  ((size_t)16 << 20)
#define ZP_OFF  ((size_t)32 << 20)
#define WS_NEED (((size_t)96) << 20)

__device__ __forceinline__ float shx(float v, int m) { return __shfl_xor(v, m, 64); }

__device__ __forceinline__ int looks_bf16(const void* p, int count) {
  const unsigned short* u = (const unsigned short*)p;
  int n = count < 64 ? count : 64;
  int good = 0;
  for (int i = 0; i < n; ++i) {
    unsigned short v = u[i];
    int e = (v >> 7) & 0xFF;
    good += (e >= 100 && e <= 140) || ((v & 0x7FFF) == 0);
  }
  return good * 8 >= n * 7;
}

__device__ __forceinline__ float ld(const void* p, int i, int isbf) {
  if (isbf) return __uint_as_float(((unsigned)((const unsigned short*)p)[i]) << 16);
  return ((const float*)p)[i];
}

// ---------------- 8-amp gate helpers (verified R3; used by fallback) -------
template<int M>
__device__ __forceinline__ void rot_x(float (&sr)[8], float (&si)[8], const float* u) {
  float4 uA = *(const float4*)u;
  float4 uB = *(const float4*)(u + 4);
  bool hi = (threadIdx.x & M) != 0;
  float ar = hi ? uB.z : uA.x, ai = hi ? uB.w : uA.y;
  float br = hi ? uB.x : uA.z, bi = hi ? uB.y : uA.w;
#pragma unroll
  for (int r = 0; r < 8; ++r) {
    float pr = shx(sr[r], M), pi = shx(si[r], M);
    float nr = ar * sr[r] - ai * si[r] + br * pr - bi * pi;
    float ni = ar * si[r] + ai * sr[r] + br * pi + bi * pr;
    sr[r] = nr; si[r] = ni;
  }
}
template<int S>
__device__ __forceinline__ void rot_r(float (&sr)[8], float (&si)[8], const float* u) {
  float4 uA = *(const float4*)u;
  float4 uB = *(const float4*)(u + 4);
#pragma unroll
  for (int r0 = 0; r0 < 8; ++r0) {
    if (r0 & S) continue;
    int r1 = r0 + S;
    float a0r = sr[r0], a0i = si[r0], a1r = sr[r1], a1i = si[r1];
    sr[r0] = uA.x * a0r - uA.y * a0i + uA.z * a1r - uA.w * a1i;
    si[r0] = uA.x * a0i + uA.y * a0r + uA.z * a1i + uA.w * a1r;
    sr[r1] = uB.x * a0r - uB.y * a0i + uB.z * a1r - uB.w * a1i;
    si[r1] = uB.x * a0i + uB.y * a0r + uB.z * a1i + uB.w * a1r;
  }
}
template<int MC, int MT>
__device__ __forceinline__ void crx_ll(float (&sr)[8], float (&si)[8], const float* cs) {
  bool ctrl = (threadIdx.x & MC) != 0;
  float c = ctrl ? cs[0] : 1.0f;
  float s = ctrl ? cs[1] : 0.0f;
#pragma unroll
  for (int r = 0; r < 8; ++r) {
    float pr = shx(sr[r], MT), pi = shx(si[r], MT);
    float nr = c * sr[r] + s * pi;
    float ni = c * si[r] - s * pr;
    sr[r] = nr; si[r] = ni;
  }
}
template<int MC, int ST>
__device__ __forceinline__ void crx_lr(float (&sr)[8], float (&si)[8], const float* cs) {
  bool ctrl = (threadIdx.x & MC) != 0;
  float c = ctrl ? cs[0] : 1.0f;
  float s = ctrl ? cs[1] : 0.0f;
#pragma unroll
  for (int r0 = 0; r0 < 8; ++r0) {
    if (r0 & ST) continue;
    int r1 = r0 + ST;
    float a0r = sr[r0], a0i = si[r0], a1r = sr[r1], a1i = si[r1];
    sr[r0] = c * a0r + s * a1i;  si[r0] = c * a0i - s * a1r;
    sr[r1] = c * a1r + s * a0i;  si[r1] = c * a1i - s * a0r;
  }
}
template<int PC, int ST>
__device__ __forceinline__ void crx_rr(float (&sr)[8], float (&si)[8], const float* cs) {
  float c = cs[0], s = cs[1];
#pragma unroll
  for (int r0 = 0; r0 < 8; ++r0) {
    if (r0 & ST) continue;
    if (!((r0 >> PC) & 1)) continue;
    int r1 = r0 + ST;
    float a0r = sr[r0], a0i = si[r0], a1r = sr[r1], a1i = si[r1];
    sr[r0] = c * a0r + s * a1i;  si[r0] = c * a0i - s * a1r;
    sr[r1] = c * a1r + s * a0i;  si[r1] = c * a1i - s * a0r;
  }
}
template<int PC, int MT>
__device__ __forceinline__ void crx_rl(float (&sr)[8], float (&si)[8], const float* cs) {
  float c = cs[0], s = cs[1];
#pragma unroll
  for (int r = 0; r < 8; ++r) {
    if (!((r >> PC) & 1)) continue;
    float pr = shx(sr[r], MT), pi = shx(si[r], MT);
    float nr = c * sr[r] + s * pi;
    float ni = c * si[r] - s * pr;
    sr[r] = nr; si[r] = ni;
  }
}

__device__ __forceinline__ void build_gates(const void* rot, const void* crx,
                                            float* gU, float* gCS) {
  int tid = threadIdx.x;
  __shared__ int gflags[2];
  if (tid == 0) {
    gflags[0] = looks_bf16(rot, NL * NQ * 3);
    gflags[1] = looks_bf16(crx, NL * NQ);
  }
  __syncthreads();
  if (tid < NL * NQ) {
    int frot = gflags[0], fcrx = gflags[1];
    float phi = ld(rot, tid * 3 + 0, frot);
    float th  = ld(rot, tid * 3 + 1, frot);
    float om  = ld(rot, tid * 3 + 2, frot);
    float c = cosf(0.5f * th), s = sinf(0.5f * th);
    float a = 0.5f * (phi + om), b = 0.5f * (phi - om);
    float ca = cosf(a), sa = sinf(a), cb = cosf(b), sb = sinf(b);
    float* u = gU + tid * 8;
    u[0] =  ca * c; u[1] = -sa * c;
    u[2] = -cb * s; u[3] = -sb * s;
    u[4] =  cb * s; u[5] = -sb * s;
    u[6] =  ca * c; u[7] =  sa * c;
    float t2 = 0.5f * ld(crx, tid, fcrx);
    gCS[tid * 2 + 0] = cosf(t2);
    gCS[tid * 2 + 1] = sinf(t2);
  }
  __syncthreads();
}

__device__ __forceinline__ void run_circuit(float (&sr)[8], float (&si)[8],
                                            const float* gU, const float* gCS) {
#pragma unroll 1
  for (int n = 0; n < NL; ++n) {
    const float* U  = gU  + n * NQ * 8;
    const float* CS = gCS + n * NQ * 2;
    rot_x<32>(sr, si, U + 0 * 8);
    rot_x<16>(sr, si, U + 1 * 8);
    rot_x< 8>(sr, si, U + 2 * 8);
    rot_x< 4>(sr, si, U + 3 * 8);
    rot_x< 2>(sr, si, U + 4 * 8);
    rot_x< 1>(sr, si, U + 5 * 8);
    rot_r< 4>(sr, si, U + 6 * 8);
    rot_r< 2>(sr, si, U + 7 * 8);
    rot_r< 1>(sr, si, U + 8 * 8);
    crx_ll<32, 16>(sr, si, CS + 0 * 2);
    crx_ll<16,  8>(sr, si, CS + 1 * 2);
    crx_ll< 8,  4>(sr, si, CS + 2 * 2);
    crx_ll< 4,  2>(sr, si, CS + 3 * 2);
    crx_ll< 2,  1>(sr, si, CS + 4 * 2);
    crx_lr< 1,  4>(sr, si, CS + 5 * 2);
    crx_rr< 2,  2>(sr, si, CS + 6 * 2);
    crx_rr< 1,  1>(sr, si, CS + 7 * 2);
    crx_rl< 0, 32>(sr, si, CS + 8 * 2);
  }
}

// ---------------- 2-amp gate helpers (4-wave-per-column wbuild) ------------
template<int M>
__device__ __forceinline__ void rot_lane2(float (&sr)[2], float (&si)[2], const float* u) {
  float4 uA = *(const float4*)u;
  float4 uB = *(const float4*)(u + 4);
  bool hi = (threadIdx.x & M) != 0;
  float ar = hi ? uB.z : uA.x, ai = hi ? uB.w : uA.y;
  float br = hi ? uB.x : uA.z, bi = hi ? uB.y : uA.w;
#pragma unroll
  for (int r = 0; r < 2; ++r) {
    float pr = shx(sr[r], M), pi = shx(si[r], M);
    float nr = ar * sr[r] - ai * si[r] + br * pr - bi * pi;
    float ni = ar * si[r] + ai * sr[r] + br * pi + bi * pr;
    sr[r] = nr; si[r] = ni;
  }
}
__device__ __forceinline__ void rot_reg2(float (&sr)[2], float (&si)[2], const float* u) {
  float4 uA = *(const float4*)u;
  float4 uB = *(const float4*)(u + 4);
  float a0r = sr[0], a0i = si[0], a1r = sr[1], a1i = si[1];
  sr[0] = uA.x * a0r - uA.y * a0i + uA.z * a1r - uA.w * a1i;
  si[0] = uA.x * a0i + uA.y * a0r + uA.z * a1i + uA.w * a1r;
  sr[1] = uB.x * a0r - uB.y * a0i + uB.z * a1r - uB.w * a1i;
  si[1] = uB.x * a0i + uB.y * a0r + uB.z * a1i + uB.w * a1r;
}
__device__ __forceinline__ void crx_lane2(float (&sr)[2], float (&si)[2],
                                          float c, float s, int MT) {
#pragma unroll
  for (int r = 0; r < 2; ++r) {
    float pr = shx(sr[r], MT), pi = shx(si[r], MT);
    float nr = c * sr[r] + s * pi;
    float ni = c * si[r] - s * pr;
    sr[r] = nr; si[r] = ni;
  }
}
__device__ __forceinline__ void crx_reg2(float (&sr)[2], float (&si)[2], float c, float s) {
  float a0r = sr[0], a0i = si[0], a1r = sr[1], a1i = si[1];
  sr[0] = c * a0r + s * a1i;  si[0] = c * a0i - s * a1r;
  sr[1] = c * a1r + s * a0i;  si[1] = c * a1i - s * a0r;
}

// -------- fused prep: blocks 0..511 build one W column each (4 waves/col),
// -------- blocks 512.. cast x->bf16 and fill remaining SIMDs ---------------
__global__ __launch_bounds__(256) void prep_kernel(const void* __restrict__ x,
                                                   const void* __restrict__ rot,
                                                   const void* __restrict__ crx,
                                                   __hip_bfloat16* __restrict__ A,
                                                   __hip_bfloat16* __restrict__ BT) {
  int tid = threadIdx.x;
  if (blockIdx.x < DIM) {
    __shared__ __align__(16) float gU[NL * NQ * 8];
    __shared__ __align__(16) float gCS[NL * NQ * 2];
    __shared__ float sRe[DIM], sIm[DIM];
    build_gates(rot, crx, gU, gCS);
    int lane = tid & 63, wv = tid >> 6;
    int idx0 = wv * 128 + lane * 2;
    int k = blockIdx.x;
    float sr[2], si[2];
    sr[0] = (idx0 == k) ? 1.f : 0.f;
    sr[1] = (idx0 + 1 == k) ? 1.f : 0.f;
    si[0] = si[1] = 0.f;
#pragma unroll 1
    for (int n = 0; n < NL; ++n) {
      const float* U  = gU  + n * NQ * 8;
      const float* CS = gCS + n * NQ * 2;
      __syncthreads();
      sRe[idx0] = sr[0]; sIm[idx0] = si[0];
      sRe[idx0 + 1] = sr[1]; sIm[idx0 + 1] = si[1];
      __syncthreads();
      {
        const float* U0 = U; const float* U1 = U + 8;
        int a = wv >> 1, b = wv & 1;
        float mr[4], mi[4];
#pragma unroll
        for (int w2 = 0; w2 < 4; ++w2) {
          int a2 = w2 >> 1, b2 = w2 & 1;
          float u0r = U0[(a * 2 + a2) * 2], u0i = U0[(a * 2 + a2) * 2 + 1];
          float u1r = U1[(b * 2 + b2) * 2], u1i = U1[(b * 2 + b2) * 2 + 1];
          mr[w2] = u0r * u1r - u0i * u1i;
          mi[w2] = u0r * u1i + u0i * u1r;
        }
#pragma unroll
        for (int r = 0; r < 2; ++r) {
          float nr = 0.f, ni = 0.f;
#pragma unroll
          for (int w2 = 0; w2 < 4; ++w2) {
            float xr = sRe[w2 * 128 + lane * 2 + r];
            float xi = sIm[w2 * 128 + lane * 2 + r];
            nr += mr[w2] * xr - mi[w2] * xi;
            ni += mr[w2] * xi + mi[w2] * xr;
          }
          sr[r] = nr; si[r] = ni;
        }
      }
      rot_lane2<32>(sr, si, U + 2 * 8);
      rot_lane2<16>(sr, si, U + 3 * 8);
      rot_lane2< 8>(sr, si, U + 4 * 8);
      rot_lane2< 4>(sr, si, U + 5 * 8);
      rot_lane2< 2>(sr, si, U + 6 * 8);
      rot_lane2< 1>(sr, si, U + 7 * 8);
      rot_reg2(sr, si, U + 8 * 8);
      __syncthreads();
      sRe[idx0] = sr[0]; sIm[idx0] = si[0];
      sRe[idx0 + 1] = sr[1]; sIm[idx0 + 1] = si[1];
      __syncthreads();
      {
        float c = (wv & 2) ? CS[0] : 1.f, s = (wv & 2) ? CS[1] : 0.f;
        int p0 = (wv ^ 1) * 128 + lane * 2;
#pragma unroll
        for (int r = 0; r < 2; ++r) {
          float pr = sRe[p0 + r], pi = sIm[p0 + r];
          float nr = c * sr[r] + s * pi;
          float ni = c * si[r] - s * pr;
          sr[r] = nr; si[r] = ni;
        }
      }
      { float c = (wv & 1) ? CS[2] : 1.f, s = (wv & 1) ? CS[3] : 0.f;
        crx_lane2(sr, si, c, s, 32); }
      { bool ct = (lane & 32); crx_lane2(sr, si, ct ? CS[4] : 1.f, ct ? CS[5] : 0.f, 16); }
      { bool ct = (lane & 16); crx_lane2(sr, si, ct ? CS[6] : 1.f, ct ? CS[7] : 0.f, 8); }
      { bool ct = (lane &  8); crx_lane2(sr, si, ct ? CS[8] : 1.f, ct ? CS[9] : 0.f, 4); }
      { bool ct = (lane &  4); crx_lane2(sr, si, ct ? CS[10] : 1.f, ct ? CS[11] : 0.f, 2); }
      { bool ct = (lane &  2); crx_lane2(sr, si, ct ? CS[12] : 1.f, ct ? CS[13] : 0.f, 1); }
      { bool ct = (lane & 1); crx_reg2(sr, si, ct ? CS[14] : 1.f, ct ? CS[15] : 0.f); }
      __syncthreads();
      sRe[idx0] = sr[0]; sIm[idx0] = si[0];
      sRe[idx0 + 1] = sr[1]; sIm[idx0 + 1] = si[1];
      __syncthreads();
      {
        float c = CS[16], s = CS[17];
        int p1 = (wv ^ 2) * 128 + lane * 2 + 1;
        float pr = sRe[p1], pi = sIm[p1];
        float nr = c * sr[1] + s * pi;
        float ni = c * si[1] - s * pr;
        sr[1] = nr; si[1] = ni;
      }
    }
#pragma unroll
    for (int r = 0; r < 2; ++r) {
      int j = idx0 + r;
      BT[(size_t)j * DIM + k]         = __float2bfloat16(sr[r]);  // Re W[j,k]
      BT[(size_t)(DIM + j) * DIM + k] = __float2bfloat16(si[r]);  // Im W[j,k]
    }
  } else {
    __shared__ int fx;
    if (tid == 0) fx = looks_bf16(x, B_TOT * DIM);
    __syncthreads();
    size_t i0 = ((size_t)(blockIdx.x - DIM) * 256 + tid) * 8;
    if (fx) {
      *(uint4*)(A + i0) = *(const uint4*)((const unsigned short*)x + i0);
    } else {
      const float4* src = (const float4*)((const float*)x + i0);
      float4 a = src[0], b = src[1];
      __hip_bfloat16 o[8];
      o[0] = __float2bfloat16(a.x); o[1] = __float2bfloat16(a.y);
      o[2] = __float2bfloat16(a.z); o[3] = __float2bfloat16(a.w);
      o[4] = __float2bfloat16(b.x); o[5] = __float2bfloat16(b.y);
      o[6] = __float2bfloat16(b.z); o[7] = __float2bfloat16(b.w);
      *(uint4*)(A + i0) = *(uint4*)o;
    }
  }
}

// ------- GEMM + fused z-reduction: Zp[panel][m][q] partials, no C ----------
// z_q(row) = sum_j sign_q(j) * |amp_j|^2, sign from bit (8-q) of j = col&511.
// Re and Im columns reduce independently (p = re^2 + im^2 splits).
// NOTE: the entire epilogue must be FULLY UNROLLED — any dynamic index into
// acc[][] demotes the accumulator array to scratch (R9: VGPR 52, 1.7 GB HBM,
// 345 us).  All loops below are constant-trip #pragma unroll.
using frag8 = __attribute__((ext_vector_type(8))) short;
using frag4 = __attribute__((ext_vector_type(4))) float;

typedef __attribute__((address_space(1))) const unsigned int GU32;
typedef __attribute__((address_space(3))) unsigned int LU32;
__device__ __forceinline__ void async16(const void* g, void* l) {
  __builtin_amdgcn_global_load_lds((GU32*)g, (LU32*)l, 16, 0, 0);
}

__global__ __launch_bounds__(256) void gemm_z_kernel(const unsigned short* __restrict__ A,
                                                     const unsigned short* __restrict__ BT,
                                                     float* __restrict__ Zp) {
  __shared__ __align__(16) unsigned short lsm[2 * 128 * 32];  // lA | lB, 16 KB
  unsigned short* lA = lsm;
  unsigned short* lB = lsm + 128 * 32;
  int bid = blockIdx.x;
  int xcd = bid & 7;
  int slot = bid >> 3;
  int n0 = (slot & 7) * 128;
  int m0 = (xcd * 16 + (slot >> 3)) * 128;
  int tid = threadIdx.x;
  int wv = tid >> 6, lane = tid & 63;
  int wm = wv >> 1, wn = wv & 1;
  int row = lane & 15, quad = lane >> 4;
  int srow = wv * 32 + (lane >> 2);
  int scol = (lane & 3) * 8;
  const unsigned short* gA = A + (size_t)(m0 + srow) * 512 + scol;
  const unsigned short* gB = BT + (size_t)(n0 + srow) * 512 + scol;
  frag4 acc[4][4] = {};
#pragma unroll 1
  for (int k0 = 0; k0 < 512; k0 += 32) {
    __syncthreads();
    async16(gA + k0,            &lA[(wv * 32) * 32]);
    async16(gA + k0 + 16 * 512, &lA[(wv * 32 + 16) * 32]);
    async16(gB + k0,            &lB[(wv * 32) * 32]);
    async16(gB + k0 + 16 * 512, &lB[(wv * 32 + 16) * 32]);
    __syncthreads();
    frag8 af[4], bf[4];
#pragma unroll
    for (int i = 0; i < 4; ++i) {
      af[i] = *(const frag8*)(&lA[(wm * 64 + i * 16 + row) * 32 + quad * 8]);
      bf[i] = *(const frag8*)(&lB[(wn * 64 + i * 16 + row) * 32 + quad * 8]);
    }
#pragma unroll
    for (int mi = 0; mi < 4; ++mi)
#pragma unroll
      for (int ni = 0; ni < 4; ++ni)
        acc[mi][ni] = __builtin_amdgcn_mfma_f32_16x16x32_bf16(af[mi], bf[ni],
                                                              acc[mi][ni], 0, 0, 0);
  }
  // ---- fused epilogue: acc tile -> z partials for 128 rows x 10 values ----
  // C/D layout: col = lane&15, row = quad*4 + reg   [verified R4-R8]
  float* zbuf = (float*)lsm;  // 2*128*10 floats = 10.2 KB, fits in 16 KB
  __syncthreads();            // all LDS frag reads done before reuse
  for (int i = tid; i < 2 * 128 * 10; i += 256) zbuf[i] = 0.f;
  __syncthreads();
  int colbase = n0 + wn * 64 + (lane & 15);
#pragma unroll
  for (int mi = 0; mi < 4; ++mi) {
    float zacc[4][10];
#pragma unroll
    for (int rg = 0; rg < 4; ++rg)
#pragma unroll
      for (int q = 0; q < 10; ++q) zacc[rg][q] = 0.f;
#pragma unroll
    for (int ni = 0; ni < 4; ++ni) {
      int j = (colbase + ni * 16) & 511;
      float sg[9];
#pragma unroll
      for (int q = 0; q < 9; ++q)
        sg[q] = ((j >> (8 - q)) & 1) ? -1.f : 1.f;
#pragma unroll
      for (int rg = 0; rg < 4; ++rg) {
        float v = acc[mi][ni][rg];
        float p = v * v;
#pragma unroll
        for (int q = 0; q < 9; ++q) zacc[rg][q] += sg[q] * p;
        zacc[rg][9] += p;
      }
    }
    // reduce over the 16 lanes of each quad (cols within this wave)
#pragma unroll
    for (int m = 1; m < 16; m <<= 1)
#pragma unroll
      for (int rg = 0; rg < 4; ++rg)
#pragma unroll
        for (int q = 0; q < 10; ++q) zacc[rg][q] += shx(zacc[rg][q], m);
    if ((lane & 15) == 0) {
      int rowl = wm * 64 + mi * 16 + quad * 4;
#pragma unroll
      for (int rg = 0; rg < 4; ++rg)
#pragma unroll
        for (int q = 0; q < 10; ++q)
          zbuf[(wn * 128 + rowl + rg) * 10 + q] = zacc[rg][q];
    }
  }
  __syncthreads();
  int panel = n0 >> 7;
  for (int i = tid; i < 128 * 10; i += 256) {
    int rowl = i / 10, q = i - rowl * 10;
    float v = zbuf[rowl * 10 + q] + zbuf[(128 + rowl) * 10 + q];
    Zp[(size_t)panel * (B_TOT * 10) + (size_t)(m0 + rowl) * 10 + q] = v;
  }
}

// ------- final reduction: sum 8 panels, normalize, logits, log_softmax -----
__global__ __launch_bounds__(256) void zred_kernel(const float* __restrict__ Zp,
                                                   const void* __restrict__ fcw,
                                                   const void* __restrict__ fcb,
                                                   float* __restrict__ out) {
  __shared__ int flags[2];
  __shared__ float sW[NCLS * NQ];
  __shared__ float sB[NCLS];
  int tid = threadIdx.x;
  if (tid == 0) {
    flags[0] = looks_bf16(fcw, NCLS * NQ);
    flags[1] = looks_bf16(fcb, NCLS);
  }
  __syncthreads();
  if (tid < NCLS * NQ) sW[tid] = ld(fcw, tid, flags[0]);
  if (tid < NCLS)      sB[tid] = ld(fcb, tid, flags[1]);
  __syncthreads();
  int row = blockIdx.x * 256 + tid;
  float z[10];
#pragma unroll
  for (int q = 0; q < 10; ++q) z[q] = 0.f;
#pragma unroll
  for (int pnl = 0; pnl < 8; ++pnl) {
    const float* p = Zp + (size_t)pnl * (B_TOT * 10) + (size_t)row * 10;
#pragma unroll
    for (int q = 0; q < 10; ++q) z[q] += p[q];
  }
  float invP = 1.0f / z[9];
#pragma unroll
  for (int q = 0; q < NQ; ++q) z[q] *= invP;
  float lg[NCLS], mx = -1e30f;
#pragma unroll
  for (int k = 0; k < NCLS; ++k) {
    float t = sB[k];
#pragma unroll
    for (int q = 0; q < NQ; ++q) t += z[q] * sW[k * NQ + q];
    lg[k] = t; mx = fmaxf(mx, t);
  }
  float se = 0.f;
#pragma unroll
  for (int k = 0; k < NCLS; ++k) se += expf(lg[k] - mx);
  float lse = mx + logf(se);
#pragma unroll
  for (int k = 0; k < NCLS; ++k) out[(size_t)row * NCLS + k] = lg[k] - lse;
}

// ---------------- fallback: round-3 passing monolithic kernel --------------
__global__ __launch_bounds__(256) void qnn_kernel(
    const void* __restrict__ x, const void* __restrict__ rot,
    const void* __restrict__ crx, const void* __restrict__ fcw,
    const void* __restrict__ fcb, float* __restrict__ out) {
  __shared__ __align__(16) float gU[NL * NQ * 8];
  __shared__ __align__(16) float gCS[NL * NQ * 2];
  __shared__ int flags[3];
  int tid = threadIdx.x;
  if (tid == 0) {
    flags[0] = looks_bf16(x, B_TOT * DIM);
    flags[1] = looks_bf16(fcw, NCLS * NQ);
    flags[2] = looks_bf16(fcb, NCLS);
  }
  build_gates(rot, crx, gU, gCS);
  __syncthreads();
  int wid = (blockIdx.x * blockDim.x + tid) >> 6;
  int lane = tid & 63;
  float sr[8], si[8];
  if (flags[0]) {
    const uint4 u = *(const uint4*)((const unsigned short*)x + (size_t)wid * DIM + lane * 8);
    sr[0] = __uint_as_float(u.x << 16); sr[1] = __uint_as_float(u.x & 0xffff0000u);
    sr[2] = __uint_as_float(u.y << 16); sr[3] = __uint_as_float(u.y & 0xffff0000u);
    sr[4] = __uint_as_float(u.z << 16); sr[5] = __uint_as_float(u.z & 0xffff0000u);
    sr[6] = __uint_as_float(u.w << 16); sr[7] = __uint_as_float(u.w & 0xffff0000u);
  } else {
    const float4* xf = (const float4*)((const float*)x + (size_t)wid * DIM) + lane * 2;
    float4 a = xf[0], b = xf[1];
    sr[0] = a.x; sr[1] = a.y; sr[2] = a.z; sr[3] = a.w;
    sr[4] = b.x; sr[5] = b.y; sr[6] = b.z; sr[7] = b.w;
  }
  float nrm = 0.f;
#pragma unroll
  for (int r = 0; r < 8; ++r) { nrm += sr[r] * sr[r]; si[r] = 0.f; }
#pragma unroll
  for (int m = 1; m < 64; m <<= 1) nrm += shx(nrm, m);
  float inv = rsqrtf(nrm);
  inv = inv * (1.5f - 0.5f * nrm * inv * inv);
#pragma unroll
  for (int r = 0; r < 8; ++r) sr[r] *= inv;
  run_circuit(sr, si, gU, gCS);
  float p[8], P = 0.f;
#pragma unroll
  for (int r = 0; r < 8; ++r) { p[r] = sr[r] * sr[r] + si[r] * si[r]; P += p[r]; }
  float z[NQ];
#pragma unroll
  for (int q = 0; q < 6; ++q) z[q] = (lane & (32 >> q)) ? -P : P;
  z[6] = z[7] = z[8] = 0.f;
#pragma unroll
  for (int r = 0; r < 8; ++r) {
    z[6] += (r & 4) ? -p[r] : p[r];
    z[7] += (r & 2) ? -p[r] : p[r];
    z[8] += (r & 1) ? -p[r] : p[r];
  }
#pragma unroll
  for (int m = 1; m < 64; m <<= 1) {
#pragma unroll
    for (int q = 0; q < NQ; ++q) z[q] += shx(z[q], m);
  }
  int ffw = flags[1], ffb = flags[2];
  float lg[NCLS], mx = -1e30f;
#pragma unroll
  for (int k = 0; k < NCLS; ++k) {
    float t = ld(fcb, k, ffb);
#pragma unroll
    for (int q = 0; q < NQ; ++q) t += z[q] * ld(fcw, k * NQ + q, ffw);
    lg[k] = t; mx = fmaxf(mx, t);
  }
  float se = 0.f;
#pragma unroll
  for (int k = 0; k < NCLS; ++k) se += expf(lg[k] - mx);
  float lse = mx + logf(se);
  if (lane < NCLS) out[(size_t)wid * NCLS + lane] = lg[lane] - lse;
}

extern "C" void kernel_launch(void* const* d_in, const int* in_sizes, int n_in,
                              void* d_out, int out_size, void* d_ws, size_t ws_size,
                              hipStream_t stream) {
  const void* x   = d_in[0];
  const void* rot = d_in[1];
  const void* crx = d_in[2];
  const void* fcw = d_in[3];
  const void* fcb = d_in[4];
  float* out = (float*)d_out;
  if (ws_size >= WS_NEED) {
    __hip_bfloat16* A  = (__hip_bfloat16*)((char*)d_ws + A_OFF);
    __hip_bfloat16* BT = (__hip_bfloat16*)((char*)d_ws + BT_OFF);
    float*          Zp = (float*)((char*)d_ws + ZP_OFF);
    prep_kernel<<<DIM + (B_TOT * DIM) / (256 * 8), 256, 0, stream>>>(x, rot, crx, A, BT);
    gemm_z_kernel<<<(B_TOT / 128) * (1024 / 128), 256, 0, stream>>>(
        (const unsigned short*)A, (const unsigned short*)BT, Zp);
    zred_kernel<<<B_TOT / 256, 256, 0, stream>>>(Zp, fcw, fcb, out);
  } else {
    qnn_kernel<<<(B_TOT * 64) / 256, 256, 0, stream>>>(x, rot, crx, fcw, fcb, out);
  }
}

// Round 11
// 145.415 us; speedup vs baseline: 3.1478x; 1.1909x over previous
//
#include <hip/hip_runtime.h>
#include <hip/hip_bf16.h>
#include <math.h>

#define NQ 9
#define NL 10
#define DIM 512
#define NCLS 10
#define B_TOT 16384

// ws layout (bytes): A bf16 [16384x512] @ 0 (16MB); BT bf16 [1024x512] @ 16MB (1MB);
// Zp f32 [8][16384][10] @ 32MB (5.25MB).  C is never materialized.
#define A_OFF   ((size_t)0)
#define BT_OFF  ((size_t)16 << 20)
#define ZP_OFF  ((size_t)32 << 20)
#define WS_NEED (((size_t)96) << 20)

__device__ __forceinline__ float shx(float v, int m) { return __shfl_xor(v, m, 64); }

__device__ __forceinline__ int looks_bf16(const void* p, int count) {
  const unsigned short* u = (const unsigned short*)p;
  int n = count < 64 ? count : 64;
  int good = 0;
  for (int i = 0; i < n; ++i) {
    unsigned short v = u[i];
    int e = (v >> 7) & 0xFF;
    good += (e >= 100 && e <= 140) || ((v & 0x7FFF) == 0);
  }
  return good * 8 >= n * 7;
}

__device__ __forceinline__ float ld(const void* p, int i, int isbf) {
  if (isbf) return __uint_as_float(((unsigned)((const unsigned short*)p)[i]) << 16);
  return ((const float*)p)[i];
}

// ---------------- 8-amp gate helpers (verified R3; used by fallback) -------
template<int M>
__device__ __forceinline__ void rot_x(float (&sr)[8], float (&si)[8], const float* u) {
  float4 uA = *(const float4*)u;
  float4 uB = *(const float4*)(u + 4);
  bool hi = (threadIdx.x & M) != 0;
  float ar = hi ? uB.z : uA.x, ai = hi ? uB.w : uA.y;
  float br = hi ? uB.x : uA.z, bi = hi ? uB.y : uA.w;
#pragma unroll
  for (int r = 0; r < 8; ++r) {
    float pr = shx(sr[r], M), pi = shx(si[r], M);
    float nr = ar * sr[r] - ai * si[r] + br * pr - bi * pi;
    float ni = ar * si[r] + ai * sr[r] + br * pi + bi * pr;
    sr[r] = nr; si[r] = ni;
  }
}
template<int S>
__device__ __forceinline__ void rot_r(float (&sr)[8], float (&si)[8], const float* u) {
  float4 uA = *(const float4*)u;
  float4 uB = *(const float4*)(u + 4);
#pragma unroll
  for (int r0 = 0; r0 < 8; ++r0) {
    if (r0 & S) continue;
    int r1 = r0 + S;
    float a0r = sr[r0], a0i = si[r0], a1r = sr[r1], a1i = si[r1];
    sr[r0] = uA.x * a0r - uA.y * a0i + uA.z * a1r - uA.w * a1i;
    si[r0] = uA.x * a0i + uA.y * a0r + uA.z * a1i + uA.w * a1r;
    sr[r1] = uB.x * a0r - uB.y * a0i + uB.z * a1r - uB.w * a1i;
    si[r1] = uB.x * a0i + uB.y * a0r + uB.z * a1i + uB.w * a1r;
  }
}
template<int MC, int MT>
__device__ __forceinline__ void crx_ll(float (&sr)[8], float (&si)[8], const float* cs) {
  bool ctrl = (threadIdx.x & MC) != 0;
  float c = ctrl ? cs[0] : 1.0f;
  float s = ctrl ? cs[1] : 0.0f;
#pragma unroll
  for (int r = 0; r < 8; ++r) {
    float pr = shx(sr[r], MT), pi = shx(si[r], MT);
    float nr = c * sr[r] + s * pi;
    float ni = c * si[r] - s * pr;
    sr[r] = nr; si[r] = ni;
  }
}
template<int MC, int ST>
__device__ __forceinline__ void crx_lr(float (&sr)[8], float (&si)[8], const float* cs) {
  bool ctrl = (threadIdx.x & MC) != 0;
  float c = ctrl ? cs[0] : 1.0f;
  float s = ctrl ? cs[1] : 0.0f;
#pragma unroll
  for (int r0 = 0; r0 < 8; ++r0) {
    if (r0 & ST) continue;
    int r1 = r0 + ST;
    float a0r = sr[r0], a0i = si[r0], a1r = sr[r1], a1i = si[r1];
    sr[r0] = c * a0r + s * a1i;  si[r0] = c * a0i - s * a1r;
    sr[r1] = c * a1r + s * a0i;  si[r1] = c * a1i - s * a0r;
  }
}
template<int PC, int ST>
__device__ __forceinline__ void crx_rr(float (&sr)[8], float (&si)[8], const float* cs) {
  float c = cs[0], s = cs[1];
#pragma unroll
  for (int r0 = 0; r0 < 8; ++r0) {
    if (r0 & ST) continue;
    if (!((r0 >> PC) & 1)) continue;
    int r1 = r0 + ST;
    float a0r = sr[r0], a0i = si[r0], a1r = sr[r1], a1i = si[r1];
    sr[r0] = c * a0r + s * a1i;  si[r0] = c * a0i - s * a1r;
    sr[r1] = c * a1r + s * a0i;  si[r1] = c * a1i - s * a0r;
  }
}
template<int PC, int MT>
__device__ __forceinline__ void crx_rl(float (&sr)[8], float (&si)[8], const float* cs) {
  float c = cs[0], s = cs[1];
#pragma unroll
  for (int r = 0; r < 8; ++r) {
    if (!((r >> PC) & 1)) continue;
    float pr = shx(sr[r], MT), pi = shx(si[r], MT);
    float nr = c * sr[r] + s * pi;
    float ni = c * si[r] - s * pr;
    sr[r] = nr; si[r] = ni;
  }
}

__device__ __forceinline__ void build_gates(const void* rot, const void* crx,
                                            float* gU, float* gCS) {
  int tid = threadIdx.x;
  __shared__ int gflags[2];
  if (tid == 0) {
    gflags[0] = looks_bf16(rot, NL * NQ * 3);
    gflags[1] = looks_bf16(crx, NL * NQ);
  }
  __syncthreads();
  if (tid < NL * NQ) {
    int frot = gflags[0], fcrx = gflags[1];
    float phi = ld(rot, tid * 3 + 0, frot);
    float th  = ld(rot, tid * 3 + 1, frot);
    float om  = ld(rot, tid * 3 + 2, frot);
    float c = cosf(0.5f * th), s = sinf(0.5f * th);
    float a = 0.5f * (phi + om), b = 0.5f * (phi - om);
    float ca = cosf(a), sa = sinf(a), cb = cosf(b), sb = sinf(b);
    float* u = gU + tid * 8;
    u[0] =  ca * c; u[1] = -sa * c;
    u[2] = -cb * s; u[3] = -sb * s;
    u[4] =  cb * s; u[5] = -sb * s;
    u[6] =  ca * c; u[7] =  sa * c;
    float t2 = 0.5f * ld(crx, tid, fcrx);
    gCS[tid * 2 + 0] = cosf(t2);
    gCS[tid * 2 + 1] = sinf(t2);
  }
  __syncthreads();
}

__device__ __forceinline__ void run_circuit(float (&sr)[8], float (&si)[8],
                                            const float* gU, const float* gCS) {
#pragma unroll 1
  for (int n = 0; n < NL; ++n) {
    const float* U  = gU  + n * NQ * 8;
    const float* CS = gCS + n * NQ * 2;
    rot_x<32>(sr, si, U + 0 * 8);
    rot_x<16>(sr, si, U + 1 * 8);
    rot_x< 8>(sr, si, U + 2 * 8);
    rot_x< 4>(sr, si, U + 3 * 8);
    rot_x< 2>(sr, si, U + 4 * 8);
    rot_x< 1>(sr, si, U + 5 * 8);
    rot_r< 4>(sr, si, U + 6 * 8);
    rot_r< 2>(sr, si, U + 7 * 8);
    rot_r< 1>(sr, si, U + 8 * 8);
    crx_ll<32, 16>(sr, si, CS + 0 * 2);
    crx_ll<16,  8>(sr, si, CS + 1 * 2);
    crx_ll< 8,  4>(sr, si, CS + 2 * 2);
    crx_ll< 4,  2>(sr, si, CS + 3 * 2);
    crx_ll< 2,  1>(sr, si, CS + 4 * 2);
    crx_lr< 1,  4>(sr, si, CS + 5 * 2);
    crx_rr< 2,  2>(sr, si, CS + 6 * 2);
    crx_rr< 1,  1>(sr, si, CS + 7 * 2);
    crx_rl< 0, 32>(sr, si, CS + 8 * 2);
  }
}

// ---------------- 2-amp gate helpers (4-wave-per-column wbuild) ------------
template<int M>
__device__ __forceinline__ void rot_lane2(float (&sr)[2], float (&si)[2], const float* u) {
  float4 uA = *(const float4*)u;
  float4 uB = *(const float4*)(u + 4);
  bool hi = (threadIdx.x & M) != 0;
  float ar = hi ? uB.z : uA.x, ai = hi ? uB.w : uA.y;
  float br = hi ? uB.x : uA.z, bi = hi ? uB.y : uA.w;
#pragma unroll
  for (int r = 0; r < 2; ++r) {
    float pr = shx(sr[r], M), pi = shx(si[r], M);
    float nr = ar * sr[r] - ai * si[r] + br * pr - bi * pi;
    float ni = ar * si[r] + ai * sr[r] + br * pi + bi * pr;
    sr[r] = nr; si[r] = ni;
  }
}
__device__ __forceinline__ void rot_reg2(float (&sr)[2], float (&si)[2], const float* u) {
  float4 uA = *(const float4*)u;
  float4 uB = *(const float4*)(u + 4);
  float a0r = sr[0], a0i = si[0], a1r = sr[1], a1i = si[1];
  sr[0] = uA.x * a0r - uA.y * a0i + uA.z * a1r - uA.w * a1i;
  si[0] = uA.x * a0i + uA.y * a0r + uA.z * a1i + uA.w * a1r;
  sr[1] = uB.x * a0r - uB.y * a0i + uB.z * a1r - uB.w * a1i;
  si[1] = uB.x * a0i + uB.y * a0r + uB.z * a1i + uB.w * a1r;
}
__device__ __forceinline__ void crx_lane2(float (&sr)[2], float (&si)[2],
                                          float c, float s, int MT) {
#pragma unroll
  for (int r = 0; r < 2; ++r) {
    float pr = shx(sr[r], MT), pi = shx(si[r], MT);
    float nr = c * sr[r] + s * pi;
    float ni = c * si[r] - s * pr;
    sr[r] = nr; si[r] = ni;
  }
}
__device__ __forceinline__ void crx_reg2(float (&sr)[2], float (&si)[2], float c, float s) {
  float a0r = sr[0], a0i = si[0], a1r = sr[1], a1i = si[1];
  sr[0] = c * a0r + s * a1i;  si[0] = c * a0i - s * a1r;
  sr[1] = c * a1r + s * a0i;  si[1] = c * a1i - s * a0r;
}

// -------- fused prep: blocks 0..511 build one W column each (4 waves/col),
// -------- blocks 512.. cast x->bf16 and fill remaining SIMDs ---------------
__global__ __launch_bounds__(256) void prep_kernel(const void* __restrict__ x,
                                                   const void* __restrict__ rot,
                                                   const void* __restrict__ crx,
                                                   __hip_bfloat16* __restrict__ A,
                                                   __hip_bfloat16* __restrict__ BT) {
  int tid = threadIdx.x;
  if (blockIdx.x < DIM) {
    __shared__ __align__(16) float gU[NL * NQ * 8];
    __shared__ __align__(16) float gCS[NL * NQ * 2];
    __shared__ float sRe[DIM], sIm[DIM];
    build_gates(rot, crx, gU, gCS);
    int lane = tid & 63, wv = tid >> 6;
    int idx0 = wv * 128 + lane * 2;
    int k = blockIdx.x;
    float sr[2], si[2];
    sr[0] = (idx0 == k) ? 1.f : 0.f;
    sr[1] = (idx0 + 1 == k) ? 1.f : 0.f;
    si[0] = si[1] = 0.f;
#pragma unroll 1
    for (int n = 0; n < NL; ++n) {
      const float* U  = gU  + n * NQ * 8;
      const float* CS = gCS + n * NQ * 2;
      __syncthreads();
      sRe[idx0] = sr[0]; sIm[idx0] = si[0];
      sRe[idx0 + 1] = sr[1]; sIm[idx0 + 1] = si[1];
      __syncthreads();
      {
        const float* U0 = U; const float* U1 = U + 8;
        int a = wv >> 1, b = wv & 1;
        float mr[4], mi[4];
#pragma unroll
        for (int w2 = 0; w2 < 4; ++w2) {
          int a2 = w2 >> 1, b2 = w2 & 1;
          float u0r = U0[(a * 2 + a2) * 2], u0i = U0[(a * 2 + a2) * 2 + 1];
          float u1r = U1[(b * 2 + b2) * 2], u1i = U1[(b * 2 + b2) * 2 + 1];
          mr[w2] = u0r * u1r - u0i * u1i;
          mi[w2] = u0r * u1i + u0i * u1r;
        }
#pragma unroll
        for (int r = 0; r < 2; ++r) {
          float nr = 0.f, ni = 0.f;
#pragma unroll
          for (int w2 = 0; w2 < 4; ++w2) {
            float xr = sRe[w2 * 128 + lane * 2 + r];
            float xi = sIm[w2 * 128 + lane * 2 + r];
            nr += mr[w2] * xr - mi[w2] * xi;
            ni += mr[w2] * xi + mi[w2] * xr;
          }
          sr[r] = nr; si[r] = ni;
        }
      }
      rot_lane2<32>(sr, si, U + 2 * 8);
      rot_lane2<16>(sr, si, U + 3 * 8);
      rot_lane2< 8>(sr, si, U + 4 * 8);
      rot_lane2< 4>(sr, si, U + 5 * 8);
      rot_lane2< 2>(sr, si, U + 6 * 8);
      rot_lane2< 1>(sr, si, U + 7 * 8);
      rot_reg2(sr, si, U + 8 * 8);
      __syncthreads();
      sRe[idx0] = sr[0]; sIm[idx0] = si[0];
      sRe[idx0 + 1] = sr[1]; sIm[idx0 + 1] = si[1];
      __syncthreads();
      {
        float c = (wv & 2) ? CS[0] : 1.f, s = (wv & 2) ? CS[1] : 0.f;
        int p0 = (wv ^ 1) * 128 + lane * 2;
#pragma unroll
        for (int r = 0; r < 2; ++r) {
          float pr = sRe[p0 + r], pi = sIm[p0 + r];
          float nr = c * sr[r] + s * pi;
          float ni = c * si[r] - s * pr;
          sr[r] = nr; si[r] = ni;
        }
      }
      { float c = (wv & 1) ? CS[2] : 1.f, s = (wv & 1) ? CS[3] : 0.f;
        crx_lane2(sr, si, c, s, 32); }
      { bool ct = (lane & 32); crx_lane2(sr, si, ct ? CS[4] : 1.f, ct ? CS[5] : 0.f, 16); }
      { bool ct = (lane & 16); crx_lane2(sr, si, ct ? CS[6] : 1.f, ct ? CS[7] : 0.f, 8); }
      { bool ct = (lane &  8); crx_lane2(sr, si, ct ? CS[8] : 1.f, ct ? CS[9] : 0.f, 4); }
      { bool ct = (lane &  4); crx_lane2(sr, si, ct ? CS[10] : 1.f, ct ? CS[11] : 0.f, 2); }
      { bool ct = (lane &  2); crx_lane2(sr, si, ct ? CS[12] : 1.f, ct ? CS[13] : 0.f, 1); }
      { bool ct = (lane & 1); crx_reg2(sr, si, ct ? CS[14] : 1.f, ct ? CS[15] : 0.f); }
      __syncthreads();
      sRe[idx0] = sr[0]; sIm[idx0] = si[0];
      sRe[idx0 + 1] = sr[1]; sIm[idx0 + 1] = si[1];
      __syncthreads();
      {
        float c = CS[16], s = CS[17];
        int p1 = (wv ^ 2) * 128 + lane * 2 + 1;
        float pr = sRe[p1], pi = sIm[p1];
        float nr = c * sr[1] + s * pi;
        float ni = c * si[1] - s * pr;
        sr[1] = nr; si[1] = ni;
      }
    }
#pragma unroll
    for (int r = 0; r < 2; ++r) {
      int j = idx0 + r;
      BT[(size_t)j * DIM + k]         = __float2bfloat16(sr[r]);  // Re W[j,k]
      BT[(size_t)(DIM + j) * DIM + k] = __float2bfloat16(si[r]);  // Im W[j,k]
    }
  } else {
    __shared__ int fx;
    if (tid == 0) fx = looks_bf16(x, B_TOT * DIM);
    __syncthreads();
    size_t i0 = ((size_t)(blockIdx.x - DIM) * 256 + tid) * 8;
    if (fx) {
      *(uint4*)(A + i0) = *(const uint4*)((const unsigned short*)x + i0);
    } else {
      const float4* src = (const float4*)((const float*)x + i0);
      float4 a = src[0], b = src[1];
      __hip_bfloat16 o[8];
      o[0] = __float2bfloat16(a.x); o[1] = __float2bfloat16(a.y);
      o[2] = __float2bfloat16(a.z); o[3] = __float2bfloat16(a.w);
      o[4] = __float2bfloat16(b.x); o[5] = __float2bfloat16(b.y);
      o[6] = __float2bfloat16(b.z); o[7] = __float2bfloat16(b.w);
      *(uint4*)(A + i0) = *(uint4*)o;
    }
  }
}

// ------- GEMM + MFMA-based z-reduction: Zp[panel][m][q], no C --------------
// z_q(row) = sum_j sign_q(j) |amp_j|^2.  Second tiny GEMM on the matrix pipe:
// Ztile[128x10] = P[128x128] . S[128x16]^T with P = acc^2 (bf16 in LDS) and
// S the +-1 sign matrix.  Replaces R10's 640-shuffle/thread butterfly that
// saturated the LDS pipe (2.1M bank-conflict cycles, 64 us).
// All acc[][] indexing stays fully unrolled (R9 scratch-spill lesson).
using frag8 = __attribute__((ext_vector_type(8))) short;
using frag4 = __attribute__((ext_vector_type(4))) float;

typedef __attribute__((address_space(1))) const unsigned int GU32;
typedef __attribute__((address_space(3))) unsigned int LU32;
__device__ __forceinline__ void async16(const void* g, void* l) {
  __builtin_amdgcn_global_load_lds((GU32*)g, (LU32*)l, 16, 0, 0);
}

#define PPITCH 136  // pA/ST row pitch in bf16 (128 + 8 pad: 16B-aligned, banks spread)

__global__ __launch_bounds__(256) void gemm_z_kernel(const unsigned short* __restrict__ A,
                                                     const unsigned short* __restrict__ BT,
                                                     float* __restrict__ Zp) {
  // union: staging lA|lB = 16KB at front; pA [128][136] bf16 = 34KB overlaps
  // staging (used after); ST [16][136] bf16 = 4.25KB disjoint at the end.
  __shared__ __align__(16) unsigned short lsm[128 * PPITCH + 16 * PPITCH];
  unsigned short* lA = lsm;
  unsigned short* lB = lsm + 128 * 32;
  unsigned short* pA = lsm;
  unsigned short* STm = lsm + 128 * PPITCH;
  int bid = blockIdx.x;
  int xcd = bid & 7;
  int slot = bid >> 3;
  int n0 = (slot & 7) * 128;
  int m0 = (xcd * 16 + (slot >> 3)) * 128;
  int tid = threadIdx.x;
  int wv = tid >> 6, lane = tid & 63;
  int wm = wv >> 1, wn = wv & 1;
  int row = lane & 15, quad = lane >> 4;
  // build sign matrix ST[q][k2] (disjoint from staging; visible after 1st barrier)
  for (int i = tid; i < 16 * 128; i += 256) {
    int q = i >> 7, k2 = i & 127;
    int j = (n0 + k2) & 511;
    float sg = (q < 9) ? (((j >> (8 - q)) & 1) ? -1.f : 1.f) : (q == 9 ? 1.f : 0.f);
    __hip_bfloat16 h = __float2bfloat16(sg);
    STm[q * PPITCH + k2] = *(unsigned short*)&h;
  }
  int srow = wv * 32 + (lane >> 2);
  int scol = (lane & 3) * 8;
  const unsigned short* gA = A + (size_t)(m0 + srow) * 512 + scol;
  const unsigned short* gB = BT + (size_t)(n0 + srow) * 512 + scol;
  frag4 acc[4][4] = {};
#pragma unroll 1
  for (int k0 = 0; k0 < 512; k0 += 32) {
    __syncthreads();
    async16(gA + k0,            &lA[(wv * 32) * 32]);
    async16(gA + k0 + 16 * 512, &lA[(wv * 32 + 16) * 32]);
    async16(gB + k0,            &lB[(wv * 32) * 32]);
    async16(gB + k0 + 16 * 512, &lB[(wv * 32 + 16) * 32]);
    __syncthreads();
    frag8 af[4], bf[4];
#pragma unroll
    for (int i = 0; i < 4; ++i) {
      af[i] = *(const frag8*)(&lA[(wm * 64 + i * 16 + row) * 32 + quad * 8]);
      bf[i] = *(const frag8*)(&lB[(wn * 64 + i * 16 + row) * 32 + quad * 8]);
    }
#pragma unroll
    for (int mi = 0; mi < 4; ++mi)
#pragma unroll
      for (int ni = 0; ni < 4; ++ni)
        acc[mi][ni] = __builtin_amdgcn_mfma_f32_16x16x32_bf16(af[mi], bf[ni],
                                                              acc[mi][ni], 0, 0, 0);
  }
  // ---- epilogue: P = acc^2 -> LDS bf16 (A-operand layout) -----------------
  __syncthreads();  // staging reads done; safe to overwrite with pA
#pragma unroll
  for (int mi = 0; mi < 4; ++mi)
#pragma unroll
    for (int ni = 0; ni < 4; ++ni)
#pragma unroll
      for (int rg = 0; rg < 4; ++rg) {
        float v = acc[mi][ni][rg];
        float p = v * v;
        int mrow = wm * 64 + mi * 16 + quad * 4 + rg;
        int k2 = wn * 64 + ni * 16 + row;
        __hip_bfloat16 h = __float2bfloat16(p);
        pA[mrow * PPITCH + k2] = *(unsigned short*)&h;
      }
  __syncthreads();
  // ---- second GEMM: Ztile = P . ST^T  (8 m-tiles, K=128; wave wv does
  // m-tiles wv and wv+4) ---------------------------------------------------
  frag8 b2[4];
#pragma unroll
  for (int kk = 0; kk < 4; ++kk)
    b2[kk] = *(const frag8*)(&STm[row * PPITCH + kk * 32 + quad * 8]);
  frag4 zacc2[2] = {};
#pragma unroll
  for (int t = 0; t < 2; ++t) {
    int mt = wv + t * 4;
#pragma unroll
    for (int kk = 0; kk < 4; ++kk) {
      frag8 a2 = *(const frag8*)(&pA[(mt * 16 + row) * PPITCH + kk * 32 + quad * 8]);
      zacc2[t] = __builtin_amdgcn_mfma_f32_16x16x32_bf16(a2, b2[kk], zacc2[t], 0, 0, 0);
    }
  }
  // C/D layout: col = lane&15 (= q), row = quad*4+rg
  int panel = n0 >> 7;
  if (row < 10) {
#pragma unroll
    for (int t = 0; t < 2; ++t) {
      int mt = wv + t * 4;
#pragma unroll
      for (int rg = 0; rg < 4; ++rg) {
        int mrow = m0 + mt * 16 + quad * 4 + rg;
        Zp[(size_t)panel * (B_TOT * 10) + (size_t)mrow * 10 + row] = zacc2[t][rg];
      }
    }
  }
}

// ------- final reduction: sum 8 panels, normalize, logits, log_softmax -----
__global__ __launch_bounds__(256) void zred_kernel(const float* __restrict__ Zp,
                                                   const void* __restrict__ fcw,
                                                   const void* __restrict__ fcb,
                                                   float* __restrict__ out) {
  __shared__ int flags[2];
  __shared__ float sW[NCLS * NQ];
  __shared__ float sB[NCLS];
  int tid = threadIdx.x;
  if (tid == 0) {
    flags[0] = looks_bf16(fcw, NCLS * NQ);
    flags[1] = looks_bf16(fcb, NCLS);
  }
  __syncthreads();
  if (tid < NCLS * NQ) sW[tid] = ld(fcw, tid, flags[0]);
  if (tid < NCLS)      sB[tid] = ld(fcb, tid, flags[1]);
  __syncthreads();
  int row = blockIdx.x * 256 + tid;
  float z[10];
#pragma unroll
  for (int q = 0; q < 10; ++q) z[q] = 0.f;
#pragma unroll
  for (int pnl = 0; pnl < 8; ++pnl) {
    const float* p = Zp + (size_t)pnl * (B_TOT * 10) + (size_t)row * 10;
#pragma unroll
    for (int q = 0; q < 10; ++q) z[q] += p[q];
  }
  float invP = 1.0f / z[9];
#pragma unroll
  for (int q = 0; q < NQ; ++q) z[q] *= invP;
  float lg[NCLS], mx = -1e30f;
#pragma unroll
  for (int k = 0; k < NCLS; ++k) {
    float t = sB[k];
#pragma unroll
    for (int q = 0; q < NQ; ++q) t += z[q] * sW[k * NQ + q];
    lg[k] = t; mx = fmaxf(mx, t);
  }
  float se = 0.f;
#pragma unroll
  for (int k = 0; k < NCLS; ++k) se += expf(lg[k] - mx);
  float lse = mx + logf(se);
#pragma unroll
  for (int k = 0; k < NCLS; ++k) out[(size_t)row * NCLS + k] = lg[k] - lse;
}

// ---------------- fallback: round-3 passing monolithic kernel --------------
__global__ __launch_bounds__(256) void qnn_kernel(
    const void* __restrict__ x, const void* __restrict__ rot,
    const void* __restrict__ crx, const void* __restrict__ fcw,
    const void* __restrict__ fcb, float* __restrict__ out) {
  __shared__ __align__(16) float gU[NL * NQ * 8];
  __shared__ __align__(16) float gCS[NL * NQ * 2];
  __shared__ int flags[3];
  int tid = threadIdx.x;
  if (tid == 0) {
    flags[0] = looks_bf16(x, B_TOT * DIM);
    flags[1] = looks_bf16(fcw, NCLS * NQ);
    flags[2] = looks_bf16(fcb, NCLS);
  }
  build_gates(rot, crx, gU, gCS);
  __syncthreads();
  int wid = (blockIdx.x * blockDim.x + tid) >> 6;
  int lane = tid & 63;
  float sr[8], si[8];
  if (flags[0]) {
    const uint4 u = *(const uint4*)((const unsigned short*)x + (size_t)wid * DIM + lane * 8);
    sr[0] = __uint_as_float(u.x << 16); sr[1] = __uint_as_float(u.x & 0xffff0000u);
    sr[2] = __uint_as_float(u.y << 16); sr[3] = __uint_as_float(u.y & 0xffff0000u);
    sr[4] = __uint_as_float(u.z << 16); sr[5] = __uint_as_float(u.z & 0xffff0000u);
    sr[6] = __uint_as_float(u.w << 16); sr[7] = __uint_as_float(u.w & 0xffff0000u);
  } else {
    const float4* xf = (const float4*)((const float*)x + (size_t)wid * DIM) + lane * 2;
    float4 a = xf[0], b = xf[1];
    sr[0] = a.x; sr[1] = a.y; sr[2] = a.z; sr[3] = a.w;
    sr[4] = b.x; sr[5] = b.y; sr[6] = b.z; sr[7] = b.w;
  }
  float nrm = 0.f;
#pragma unroll
  for (int r = 0; r < 8; ++r) { nrm += sr[r] * sr[r]; si[r] = 0.f; }
#pragma unroll
  for (int m = 1; m < 64; m <<= 1) nrm += shx(nrm, m);
  float inv = rsqrtf(nrm);
  inv = inv * (1.5f - 0.5f * nrm * inv * inv);
#pragma unroll
  for (int r = 0; r < 8; ++r) sr[r] *= inv;
  run_circuit(sr, si, gU, gCS);
  float p[8], P = 0.f;
#pragma unroll
  for (int r = 0; r < 8; ++r) { p[r] = sr[r] * sr[r] + si[r] * si[r]; P += p[r]; }
  float z[NQ];
#pragma unroll
  for (int q = 0; q < 6; ++q) z[q] = (lane & (32 >> q)) ? -P : P;
  z[6] = z[7] = z[8] = 0.f;
#pragma unroll
  for (int r = 0; r < 8; ++r) {
    z[6] += (r & 4) ? -p[r] : p[r];
    z[7] += (r & 2) ? -p[r] : p[r];
    z[8] += (r & 1) ? -p[r] : p[r];
  }
#pragma unroll
  for (int m = 1; m < 64; m <<= 1) {
#pragma unroll
    for (int q = 0; q < NQ; ++q) z[q] += shx(z[q], m);
  }
  int ffw = flags[1], ffb = flags[2];
  float lg[NCLS], mx = -1e30f;
#pragma unroll
  for (int k = 0; k < NCLS; ++k) {
    float t = ld(fcb, k, ffb);
#pragma unroll
    for (int q = 0; q < NQ; ++q) t += z[q] * ld(fcw, k * NQ + q, ffw);
    lg[k] = t; mx = fmaxf(mx, t);
  }
  float se = 0.f;
#pragma unroll
  for (int k = 0; k < NCLS; ++k) se += expf(lg[k] - mx);
  float lse = mx + logf(se);
  if (lane < NCLS) out[(size_t)wid * NCLS + lane] = lg[lane] - lse;
}

extern "C" void kernel_launch(void* const* d_in, const int* in_sizes, int n_in,
                              void* d_out, int out_size, void* d_ws, size_t ws_size,
                              hipStream_t stream) {
  const void* x   = d_in[0];
  const void* rot = d_in[1];
  const void* crx = d_in[2];
  const void* fcw = d_in[3];
  const void* fcb = d_in[4];
  float* out = (float*)d_out;
  if (ws_size >= WS_NEED) {
    __hip_bfloat16* A  = (__hip_bfloat16*)((char*)d_ws + A_OFF);
    __hip_bfloat16* BT = (__hip_bfloat16*)((char*)d_ws + BT_OFF);
    float*          Zp = (float*)((char*)d_ws + ZP_OFF);
    prep_kernel<<<DIM + (B_TOT * DIM) / (256 * 8), 256, 0, stream>>>(x, rot, crx, A, BT);
    gemm_z_kernel<<<(B_TOT / 128) * (1024 / 128), 256, 0, stream>>>(
        (const unsigned short*)A, (const unsigned short*)BT, Zp);
    zred_kernel<<<B_TOT / 256, 256, 0, stream>>>(Zp, fcw, fcb, out);
  } else {
    qnn_kernel<<<(B_TOT * 64) / 256, 256, 0, stream>>>(x, rot, crx, fcw, fcb, out);
  }
}

// Round 12
// 141.966 us; speedup vs baseline: 3.2242x; 1.0243x over previous
//
#include <hip/hip_runtime.h>
#include <hip/hip_bf16.h>
#include <math.h>

#define NQ 9
#define NL 10
#define DIM 512
#define NCLS 10
#define B_TOT 16384

// ws layout (bytes): A bf16 [16384x512] @ 0 (16MB); BT bf16 [1024x512] @ 16MB (1MB);
// Zp f32 [8][16384][10] @ 32MB (5.25MB).  C is never materialized.
#define A_OFF   ((size_t)0)
#define BT_OFF  ((size_t)16 << 20)
#define ZP_OFF  ((size_t)32 << 20)
#define WS_NEED (((size_t)96) << 20)

__device__ __forceinline__ float shx(float v, int m) { return __shfl_xor(v, m, 64); }

__device__ __forceinline__ int looks_bf16(const void* p, int count) {
  const unsigned short* u = (const unsigned short*)p;
  int n = count < 64 ? count : 64;
  int good = 0;
  for (int i = 0; i < n; ++i) {
    unsigned short v = u[i];
    int e = (v >> 7) & 0xFF;
    good += (e >= 100 && e <= 140) || ((v & 0x7FFF) == 0);
  }
  return good * 8 >= n * 7;
}

__device__ __forceinline__ float ld(const void* p, int i, int isbf) {
  if (isbf) return __uint_as_float(((unsigned)((const unsigned short*)p)[i]) << 16);
  return ((const float*)p)[i];
}

// ---------------- 8-amp gate helpers (verified R3; used by fallback) -------
template<int M>
__device__ __forceinline__ void rot_x(float (&sr)[8], float (&si)[8], const float* u) {
  float4 uA = *(const float4*)u;
  float4 uB = *(const float4*)(u + 4);
  bool hi = (threadIdx.x & M) != 0;
  float ar = hi ? uB.z : uA.x, ai = hi ? uB.w : uA.y;
  float br = hi ? uB.x : uA.z, bi = hi ? uB.y : uA.w;
#pragma unroll
  for (int r = 0; r < 8; ++r) {
    float pr = shx(sr[r], M), pi = shx(si[r], M);
    float nr = ar * sr[r] - ai * si[r] + br * pr - bi * pi;
    float ni = ar * si[r] + ai * sr[r] + br * pi + bi * pr;
    sr[r] = nr; si[r] = ni;
  }
}
template<int S>
__device__ __forceinline__ void rot_r(float (&sr)[8], float (&si)[8], const float* u) {
  float4 uA = *(const float4*)u;
  float4 uB = *(const float4*)(u + 4);
#pragma unroll
  for (int r0 = 0; r0 < 8; ++r0) {
    if (r0 & S) continue;
    int r1 = r0 + S;
    float a0r = sr[r0], a0i = si[r0], a1r = sr[r1], a1i = si[r1];
    sr[r0] = uA.x * a0r - uA.y * a0i + uA.z * a1r - uA.w * a1i;
    si[r0] = uA.x * a0i + uA.y * a0r + uA.z * a1i + uA.w * a1r;
    sr[r1] = uB.x * a0r - uB.y * a0i + uB.z * a1r - uB.w * a1i;
    si[r1] = uB.x * a0i + uB.y * a0r + uB.z * a1i + uB.w * a1r;
  }
}
template<int MC, int MT>
__device__ __forceinline__ void crx_ll(float (&sr)[8], float (&si)[8], const float* cs) {
  bool ctrl = (threadIdx.x & MC) != 0;
  float c = ctrl ? cs[0] : 1.0f;
  float s = ctrl ? cs[1] : 0.0f;
#pragma unroll
  for (int r = 0; r < 8; ++r) {
    float pr = shx(sr[r], MT), pi = shx(si[r], MT);
    float nr = c * sr[r] + s * pi;
    float ni = c * si[r] - s * pr;
    sr[r] = nr; si[r] = ni;
  }
}
template<int MC, int ST>
__device__ __forceinline__ void crx_lr(float (&sr)[8], float (&si)[8], const float* cs) {
  bool ctrl = (threadIdx.x & MC) != 0;
  float c = ctrl ? cs[0] : 1.0f;
  float s = ctrl ? cs[1] : 0.0f;
#pragma unroll
  for (int r0 = 0; r0 < 8; ++r0) {
    if (r0 & ST) continue;
    int r1 = r0 + ST;
    float a0r = sr[r0], a0i = si[r0], a1r = sr[r1], a1i = si[r1];
    sr[r0] = c * a0r + s * a1i;  si[r0] = c * a0i - s * a1r;
    sr[r1] = c * a1r + s * a0i;  si[r1] = c * a1i - s * a0r;
  }
}
template<int PC, int ST>
__device__ __forceinline__ void crx_rr(float (&sr)[8], float (&si)[8], const float* cs) {
  float c = cs[0], s = cs[1];
#pragma unroll
  for (int r0 = 0; r0 < 8; ++r0) {
    if (r0 & ST) continue;
    if (!((r0 >> PC) & 1)) continue;
    int r1 = r0 + ST;
    float a0r = sr[r0], a0i = si[r0], a1r = sr[r1], a1i = si[r1];
    sr[r0] = c * a0r + s * a1i;  si[r0] = c * a0i - s * a1r;
    sr[r1] = c * a1r + s * a0i;  si[r1] = c * a1i - s * a0r;
  }
}
template<int PC, int MT>
__device__ __forceinline__ void crx_rl(float (&sr)[8], float (&si)[8], const float* cs) {
  float c = cs[0], s = cs[1];
#pragma unroll
  for (int r = 0; r < 8; ++r) {
    if (!((r >> PC) & 1)) continue;
    float pr = shx(sr[r], MT), pi = shx(si[r], MT);
    float nr = c * sr[r] + s * pi;
    float ni = c * si[r] - s * pr;
    sr[r] = nr; si[r] = ni;
  }
}

__device__ __forceinline__ void build_gates(const void* rot, const void* crx,
                                            float* gU, float* gCS) {
  int tid = threadIdx.x;
  __shared__ int gflags[2];
  if (tid == 0) {
    gflags[0] = looks_bf16(rot, NL * NQ * 3);
    gflags[1] = looks_bf16(crx, NL * NQ);
  }
  __syncthreads();
  if (tid < NL * NQ) {
    int frot = gflags[0], fcrx = gflags[1];
    float phi = ld(rot, tid * 3 + 0, frot);
    float th  = ld(rot, tid * 3 + 1, frot);
    float om  = ld(rot, tid * 3 + 2, frot);
    float c = cosf(0.5f * th), s = sinf(0.5f * th);
    float a = 0.5f * (phi + om), b = 0.5f * (phi - om);
    float ca = cosf(a), sa = sinf(a), cb = cosf(b), sb = sinf(b);
    float* u = gU + tid * 8;
    u[0] =  ca * c; u[1] = -sa * c;
    u[2] = -cb * s; u[3] = -sb * s;
    u[4] =  cb * s; u[5] = -sb * s;
    u[6] =  ca * c; u[7] =  sa * c;
    float t2 = 0.5f * ld(crx, tid, fcrx);
    gCS[tid * 2 + 0] = cosf(t2);
    gCS[tid * 2 + 1] = sinf(t2);
  }
  __syncthreads();
}

__device__ __forceinline__ void run_circuit(float (&sr)[8], float (&si)[8],
                                            const float* gU, const float* gCS) {
#pragma unroll 1
  for (int n = 0; n < NL; ++n) {
    const float* U  = gU  + n * NQ * 8;
    const float* CS = gCS + n * NQ * 2;
    rot_x<32>(sr, si, U + 0 * 8);
    rot_x<16>(sr, si, U + 1 * 8);
    rot_x< 8>(sr, si, U + 2 * 8);
    rot_x< 4>(sr, si, U + 3 * 8);
    rot_x< 2>(sr, si, U + 4 * 8);
    rot_x< 1>(sr, si, U + 5 * 8);
    rot_r< 4>(sr, si, U + 6 * 8);
    rot_r< 2>(sr, si, U + 7 * 8);
    rot_r< 1>(sr, si, U + 8 * 8);
    crx_ll<32, 16>(sr, si, CS + 0 * 2);
    crx_ll<16,  8>(sr, si, CS + 1 * 2);
    crx_ll< 8,  4>(sr, si, CS + 2 * 2);
    crx_ll< 4,  2>(sr, si, CS + 3 * 2);
    crx_ll< 2,  1>(sr, si, CS + 4 * 2);
    crx_lr< 1,  4>(sr, si, CS + 5 * 2);
    crx_rr< 2,  2>(sr, si, CS + 6 * 2);
    crx_rr< 1,  1>(sr, si, CS + 7 * 2);
    crx_rl< 0, 32>(sr, si, CS + 8 * 2);
  }
}

// ---------------- 2-amp gate helpers (4-wave-per-column wbuild) ------------
template<int M>
__device__ __forceinline__ void rot_lane2(float (&sr)[2], float (&si)[2], const float* u) {
  float4 uA = *(const float4*)u;
  float4 uB = *(const float4*)(u + 4);
  bool hi = (threadIdx.x & M) != 0;
  float ar = hi ? uB.z : uA.x, ai = hi ? uB.w : uA.y;
  float br = hi ? uB.x : uA.z, bi = hi ? uB.y : uA.w;
#pragma unroll
  for (int r = 0; r < 2; ++r) {
    float pr = shx(sr[r], M), pi = shx(si[r], M);
    float nr = ar * sr[r] - ai * si[r] + br * pr - bi * pi;
    float ni = ar * si[r] + ai * sr[r] + br * pi + bi * pr;
    sr[r] = nr; si[r] = ni;
  }
}
__device__ __forceinline__ void rot_reg2(float (&sr)[2], float (&si)[2], const float* u) {
  float4 uA = *(const float4*)u;
  float4 uB = *(const float4*)(u + 4);
  float a0r = sr[0], a0i = si[0], a1r = sr[1], a1i = si[1];
  sr[0] = uA.x * a0r - uA.y * a0i + uA.z * a1r - uA.w * a1i;
  si[0] = uA.x * a0i + uA.y * a0r + uA.z * a1i + uA.w * a1r;
  sr[1] = uB.x * a0r - uB.y * a0i + uB.z * a1r - uB.w * a1i;
  si[1] = uB.x * a0i + uB.y * a0r + uB.z * a1i + uB.w * a1r;
}
__device__ __forceinline__ void crx_lane2(float (&sr)[2], float (&si)[2],
                                          float c, float s, int MT) {
#pragma unroll
  for (int r = 0; r < 2; ++r) {
    float pr = shx(sr[r], MT), pi = shx(si[r], MT);
    float nr = c * sr[r] + s * pi;
    float ni = c * si[r] - s * pr;
    sr[r] = nr; si[r] = ni;
  }
}
__device__ __forceinline__ void crx_reg2(float (&sr)[2], float (&si)[2], float c, float s) {
  float a0r = sr[0], a0i = si[0], a1r = sr[1], a1i = si[1];
  sr[0] = c * a0r + s * a1i;  si[0] = c * a0i - s * a1r;
  sr[1] = c * a1r + s * a0i;  si[1] = c * a1i - s * a0r;
}

// -------- fused prep: blocks 0..511 build one W column each (4 waves/col),
// -------- blocks 512.. cast x->bf16 and fill remaining SIMDs ---------------
__global__ __launch_bounds__(256) void prep_kernel(const void* __restrict__ x,
                                                   const void* __restrict__ rot,
                                                   const void* __restrict__ crx,
                                                   __hip_bfloat16* __restrict__ A,
                                                   __hip_bfloat16* __restrict__ BT) {
  int tid = threadIdx.x;
  if (blockIdx.x < DIM) {
    __shared__ __align__(16) float gU[NL * NQ * 8];
    __shared__ __align__(16) float gCS[NL * NQ * 2];
    __shared__ float sRe[DIM], sIm[DIM];
    build_gates(rot, crx, gU, gCS);
    int lane = tid & 63, wv = tid >> 6;
    int idx0 = wv * 128 + lane * 2;
    int k = blockIdx.x;
    float sr[2], si[2];
    sr[0] = (idx0 == k) ? 1.f : 0.f;
    sr[1] = (idx0 + 1 == k) ? 1.f : 0.f;
    si[0] = si[1] = 0.f;
#pragma unroll 1
    for (int n = 0; n < NL; ++n) {
      const float* U  = gU  + n * NQ * 8;
      const float* CS = gCS + n * NQ * 2;
      __syncthreads();
      sRe[idx0] = sr[0]; sIm[idx0] = si[0];
      sRe[idx0 + 1] = sr[1]; sIm[idx0 + 1] = si[1];
      __syncthreads();
      {
        const float* U0 = U; const float* U1 = U + 8;
        int a = wv >> 1, b = wv & 1;
        float mr[4], mi[4];
#pragma unroll
        for (int w2 = 0; w2 < 4; ++w2) {
          int a2 = w2 >> 1, b2 = w2 & 1;
          float u0r = U0[(a * 2 + a2) * 2], u0i = U0[(a * 2 + a2) * 2 + 1];
          float u1r = U1[(b * 2 + b2) * 2], u1i = U1[(b * 2 + b2) * 2 + 1];
          mr[w2] = u0r * u1r - u0i * u1i;
          mi[w2] = u0r * u1i + u0i * u1r;
        }
#pragma unroll
        for (int r = 0; r < 2; ++r) {
          float nr = 0.f, ni = 0.f;
#pragma unroll
          for (int w2 = 0; w2 < 4; ++w2) {
            float xr = sRe[w2 * 128 + lane * 2 + r];
            float xi = sIm[w2 * 128 + lane * 2 + r];
            nr += mr[w2] * xr - mi[w2] * xi;
            ni += mr[w2] * xi + mi[w2] * xr;
          }
          sr[r] = nr; si[r] = ni;
        }
      }
      rot_lane2<32>(sr, si, U + 2 * 8);
      rot_lane2<16>(sr, si, U + 3 * 8);
      rot_lane2< 8>(sr, si, U + 4 * 8);
      rot_lane2< 4>(sr, si, U + 5 * 8);
      rot_lane2< 2>(sr, si, U + 6 * 8);
      rot_lane2< 1>(sr, si, U + 7 * 8);
      rot_reg2(sr, si, U + 8 * 8);
      __syncthreads();
      sRe[idx0] = sr[0]; sIm[idx0] = si[0];
      sRe[idx0 + 1] = sr[1]; sIm[idx0 + 1] = si[1];
      __syncthreads();
      {
        float c = (wv & 2) ? CS[0] : 1.f, s = (wv & 2) ? CS[1] : 0.f;
        int p0 = (wv ^ 1) * 128 + lane * 2;
#pragma unroll
        for (int r = 0; r < 2; ++r) {
          float pr = sRe[p0 + r], pi = sIm[p0 + r];
          float nr = c * sr[r] + s * pi;
          float ni = c * si[r] - s * pr;
          sr[r] = nr; si[r] = ni;
        }
      }
      { float c = (wv & 1) ? CS[2] : 1.f, s = (wv & 1) ? CS[3] : 0.f;
        crx_lane2(sr, si, c, s, 32); }
      { bool ct = (lane & 32); crx_lane2(sr, si, ct ? CS[4] : 1.f, ct ? CS[5] : 0.f, 16); }
      { bool ct = (lane & 16); crx_lane2(sr, si, ct ? CS[6] : 1.f, ct ? CS[7] : 0.f, 8); }
      { bool ct = (lane &  8); crx_lane2(sr, si, ct ? CS[8] : 1.f, ct ? CS[9] : 0.f, 4); }
      { bool ct = (lane &  4); crx_lane2(sr, si, ct ? CS[10] : 1.f, ct ? CS[11] : 0.f, 2); }
      { bool ct = (lane &  2); crx_lane2(sr, si, ct ? CS[12] : 1.f, ct ? CS[13] : 0.f, 1); }
      { bool ct = (lane & 1); crx_reg2(sr, si, ct ? CS[14] : 1.f, ct ? CS[15] : 0.f); }
      __syncthreads();
      sRe[idx0] = sr[0]; sIm[idx0] = si[0];
      sRe[idx0 + 1] = sr[1]; sIm[idx0 + 1] = si[1];
      __syncthreads();
      {
        float c = CS[16], s = CS[17];
        int p1 = (wv ^ 2) * 128 + lane * 2 + 1;
        float pr = sRe[p1], pi = sIm[p1];
        float nr = c * sr[1] + s * pi;
        float ni = c * si[1] - s * pr;
        sr[1] = nr; si[1] = ni;
      }
    }
#pragma unroll
    for (int r = 0; r < 2; ++r) {
      int j = idx0 + r;
      BT[(size_t)j * DIM + k]         = __float2bfloat16(sr[r]);  // Re W[j,k]
      BT[(size_t)(DIM + j) * DIM + k] = __float2bfloat16(si[r]);  // Im W[j,k]
    }
  } else {
    __shared__ int fx;
    if (tid == 0) fx = looks_bf16(x, B_TOT * DIM);
    __syncthreads();
    size_t i0 = ((size_t)(blockIdx.x - DIM) * 256 + tid) * 8;
    if (fx) {
      *(uint4*)(A + i0) = *(const uint4*)((const unsigned short*)x + i0);
    } else {
      const float4* src = (const float4*)((const float*)x + i0);
      float4 a = src[0], b = src[1];
      __hip_bfloat16 o[8];
      o[0] = __float2bfloat16(a.x); o[1] = __float2bfloat16(a.y);
      o[2] = __float2bfloat16(a.z); o[3] = __float2bfloat16(a.w);
      o[4] = __float2bfloat16(b.x); o[5] = __float2bfloat16(b.y);
      o[6] = __float2bfloat16(b.z); o[7] = __float2bfloat16(b.w);
      *(uint4*)(A + i0) = *(uint4*)o;
    }
  }
}

// ------- GEMM (BK=64) + MFMA-based z-reduction: Zp[panel][m][q], no C ------
// BK=64 as two proven 32-col staging panels per iteration -> 8 barrier-drain
// iterations instead of 16 (the vmcnt(0)+barrier drain was first-order at
// K=512).  Panel layout & frag mapping identical to the verified BK=32 one.
// All acc[][] indexing fully unrolled (R9 scratch-spill lesson).
using frag8 = __attribute__((ext_vector_type(8))) short;
using frag4 = __attribute__((ext_vector_type(4))) float;

typedef __attribute__((address_space(1))) const unsigned int GU32;
typedef __attribute__((address_space(3))) unsigned int LU32;
__device__ __forceinline__ void async16(const void* g, void* l) {
  __builtin_amdgcn_global_load_lds((GU32*)g, (LU32*)l, 16, 0, 0);
}

#define PPITCH 136  // pA/ST row pitch in bf16 (128 + 8 pad)
#define PANEL (128 * 32)

__global__ __launch_bounds__(256) void gemm_z_kernel(const unsigned short* __restrict__ A,
                                                     const unsigned short* __restrict__ BT,
                                                     float* __restrict__ Zp) {
  // union: staging lA0|lA1|lB0|lB1 = 32KB at front; pA [128][136] bf16 =
  // 34.8KB overlaps staging (used after); ST [16][136] disjoint at the end.
  __shared__ __align__(16) unsigned short lsm[128 * PPITCH + 16 * PPITCH];
  unsigned short* lA0 = lsm;
  unsigned short* lA1 = lsm + PANEL;
  unsigned short* lB0 = lsm + 2 * PANEL;
  unsigned short* lB1 = lsm + 3 * PANEL;
  unsigned short* pA  = lsm;
  unsigned short* STm = lsm + 128 * PPITCH;
  int bid = blockIdx.x;
  int xcd = bid & 7;
  int slot = bid >> 3;
  int n0 = (slot & 7) * 128;
  int m0 = (xcd * 16 + (slot >> 3)) * 128;
  int tid = threadIdx.x;
  int wv = tid >> 6, lane = tid & 63;
  int wm = wv >> 1, wn = wv & 1;
  int row = lane & 15, quad = lane >> 4;
  // build sign matrix ST[q][k2] (disjoint from staging)
  for (int i = tid; i < 16 * 128; i += 256) {
    int q = i >> 7, k2 = i & 127;
    int j = (n0 + k2) & 511;
    float sg = (q < 9) ? (((j >> (8 - q)) & 1) ? -1.f : 1.f) : (q == 9 ? 1.f : 0.f);
    __hip_bfloat16 h = __float2bfloat16(sg);
    STm[q * PPITCH + k2] = *(unsigned short*)&h;
  }
  int srow = wv * 32 + (lane >> 2);
  int scol = (lane & 3) * 8;
  const unsigned short* gA = A + (size_t)(m0 + srow) * 512 + scol;
  const unsigned short* gB = BT + (size_t)(n0 + srow) * 512 + scol;
  frag4 acc[4][4] = {};
#pragma unroll 1
  for (int k0 = 0; k0 < 512; k0 += 64) {
    __syncthreads();
    // panel 0: cols k0..k0+32, panel 1: cols k0+32..k0+64
    async16(gA + k0,                 &lA0[(wv * 32) * 32]);
    async16(gA + k0 + 16 * 512,      &lA0[(wv * 32 + 16) * 32]);
    async16(gA + k0 + 32,            &lA1[(wv * 32) * 32]);
    async16(gA + k0 + 32 + 16 * 512, &lA1[(wv * 32 + 16) * 32]);
    async16(gB + k0,                 &lB0[(wv * 32) * 32]);
    async16(gB + k0 + 16 * 512,      &lB0[(wv * 32 + 16) * 32]);
    async16(gB + k0 + 32,            &lB1[(wv * 32) * 32]);
    async16(gB + k0 + 32 + 16 * 512, &lB1[(wv * 32 + 16) * 32]);
    __syncthreads();
    // kc = 0
    {
      frag8 af[4], bf[4];
#pragma unroll
      for (int i = 0; i < 4; ++i) {
        af[i] = *(const frag8*)(&lA0[(wm * 64 + i * 16 + row) * 32 + quad * 8]);
        bf[i] = *(const frag8*)(&lB0[(wn * 64 + i * 16 + row) * 32 + quad * 8]);
      }
#pragma unroll
      for (int mi = 0; mi < 4; ++mi)
#pragma unroll
        for (int ni = 0; ni < 4; ++ni)
          acc[mi][ni] = __builtin_amdgcn_mfma_f32_16x16x32_bf16(af[mi], bf[ni],
                                                                acc[mi][ni], 0, 0, 0);
    }
    // kc = 1
    {
      frag8 af[4], bf[4];
#pragma unroll
      for (int i = 0; i < 4; ++i) {
        af[i] = *(const frag8*)(&lA1[(wm * 64 + i * 16 + row) * 32 + quad * 8]);
        bf[i] = *(const frag8*)(&lB1[(wn * 64 + i * 16 + row) * 32 + quad * 8]);
      }
#pragma unroll
      for (int mi = 0; mi < 4; ++mi)
#pragma unroll
        for (int ni = 0; ni < 4; ++ni)
          acc[mi][ni] = __builtin_amdgcn_mfma_f32_16x16x32_bf16(af[mi], bf[ni],
                                                                acc[mi][ni], 0, 0, 0);
    }
  }
  // ---- epilogue: P = acc^2 -> LDS bf16 (A-operand layout) -----------------
  __syncthreads();  // staging reads done; safe to overwrite with pA
#pragma unroll
  for (int mi = 0; mi < 4; ++mi)
#pragma unroll
    for (int ni = 0; ni < 4; ++ni)
#pragma unroll
      for (int rg = 0; rg < 4; ++rg) {
        float v = acc[mi][ni][rg];
        float p = v * v;
        int mrow = wm * 64 + mi * 16 + quad * 4 + rg;
        int k2 = wn * 64 + ni * 16 + row;
        __hip_bfloat16 h = __float2bfloat16(p);
        pA[mrow * PPITCH + k2] = *(unsigned short*)&h;
      }
  __syncthreads();
  // ---- second GEMM: Ztile = P . ST^T (8 m-tiles; wave wv does wv, wv+4) ---
  frag8 b2[4];
#pragma unroll
  for (int kk = 0; kk < 4; ++kk)
    b2[kk] = *(const frag8*)(&STm[row * PPITCH + kk * 32 + quad * 8]);
  frag4 zacc2[2] = {};
#pragma unroll
  for (int t = 0; t < 2; ++t) {
    int mt = wv + t * 4;
#pragma unroll
    for (int kk = 0; kk < 4; ++kk) {
      frag8 a2 = *(const frag8*)(&pA[(mt * 16 + row) * PPITCH + kk * 32 + quad * 8]);
      zacc2[t] = __builtin_amdgcn_mfma_f32_16x16x32_bf16(a2, b2[kk], zacc2[t], 0, 0, 0);
    }
  }
  // C/D layout: col = lane&15 (= q), row = quad*4+rg
  int panel = n0 >> 7;
  if (row < 10) {
#pragma unroll
    for (int t = 0; t < 2; ++t) {
      int mt = wv + t * 4;
#pragma unroll
      for (int rg = 0; rg < 4; ++rg) {
        int mrow = m0 + mt * 16 + quad * 4 + rg;
        Zp[(size_t)panel * (B_TOT * 10) + (size_t)mrow * 10 + row] = zacc2[t][rg];
      }
    }
  }
}

// ------- final reduction: sum 8 panels, normalize, logits, log_softmax -----
__global__ __launch_bounds__(256) void zred_kernel(const float* __restrict__ Zp,
                                                   const void* __restrict__ fcw,
                                                   const void* __restrict__ fcb,
                                                   float* __restrict__ out) {
  __shared__ int flags[2];
  __shared__ float sW[NCLS * NQ];
  __shared__ float sB[NCLS];
  int tid = threadIdx.x;
  if (tid == 0) {
    flags[0] = looks_bf16(fcw, NCLS * NQ);
    flags[1] = looks_bf16(fcb, NCLS);
  }
  __syncthreads();
  if (tid < NCLS * NQ) sW[tid] = ld(fcw, tid, flags[0]);
  if (tid < NCLS)      sB[tid] = ld(fcb, tid, flags[1]);
  __syncthreads();
  int row = blockIdx.x * 256 + tid;
  float z[10];
#pragma unroll
  for (int q = 0; q < 10; ++q) z[q] = 0.f;
#pragma unroll
  for (int pnl = 0; pnl < 8; ++pnl) {
    const float* p = Zp + (size_t)pnl * (B_TOT * 10) + (size_t)row * 10;
#pragma unroll
    for (int q = 0; q < 10; ++q) z[q] += p[q];
  }
  float invP = 1.0f / z[9];
#pragma unroll
  for (int q = 0; q < NQ; ++q) z[q] *= invP;
  float lg[NCLS], mx = -1e30f;
#pragma unroll
  for (int k = 0; k < NCLS; ++k) {
    float t = sB[k];
#pragma unroll
    for (int q = 0; q < NQ; ++q) t += z[q] * sW[k * NQ + q];
    lg[k] = t; mx = fmaxf(mx, t);
  }
  float se = 0.f;
#pragma unroll
  for (int k = 0; k < NCLS; ++k) se += expf(lg[k] - mx);
  float lse = mx + logf(se);
#pragma unroll
  for (int k = 0; k < NCLS; ++k) out[(size_t)row * NCLS + k] = lg[k] - lse;
}

// ---------------- fallback: round-3 passing monolithic kernel --------------
__global__ __launch_bounds__(256) void qnn_kernel(
    const void* __restrict__ x, const void* __restrict__ rot,
    const void* __restrict__ crx, const void* __restrict__ fcw,
    const void* __restrict__ fcb, float* __restrict__ out) {
  __shared__ __align__(16) float gU[NL * NQ * 8];
  __shared__ __align__(16) float gCS[NL * NQ * 2];
  __shared__ int flags[3];
  int tid = threadIdx.x;
  if (tid == 0) {
    flags[0] = looks_bf16(x, B_TOT * DIM);
    flags[1] = looks_bf16(fcw, NCLS * NQ);
    flags[2] = looks_bf16(fcb, NCLS);
  }
  build_gates(rot, crx, gU, gCS);
  __syncthreads();
  int wid = (blockIdx.x * blockDim.x + tid) >> 6;
  int lane = tid & 63;
  float sr[8], si[8];
  if (flags[0]) {
    const uint4 u = *(const uint4*)((const unsigned short*)x + (size_t)wid * DIM + lane * 8);
    sr[0] = __uint_as_float(u.x << 16); sr[1] = __uint_as_float(u.x & 0xffff0000u);
    sr[2] = __uint_as_float(u.y << 16); sr[3] = __uint_as_float(u.y & 0xffff0000u);
    sr[4] = __uint_as_float(u.z << 16); sr[5] = __uint_as_float(u.z & 0xffff0000u);
    sr[6] = __uint_as_float(u.w << 16); sr[7] = __uint_as_float(u.w & 0xffff0000u);
  } else {
    const float4* xf = (const float4*)((const float*)x + (size_t)wid * DIM) + lane * 2;
    float4 a = xf[0], b = xf[1];
    sr[0] = a.x; sr[1] = a.y; sr[2] = a.z; sr[3] = a.w;
    sr[4] = b.x; sr[5] = b.y; sr[6] = b.z; sr[7] = b.w;
  }
  float nrm = 0.f;
#pragma unroll
  for (int r = 0; r < 8; ++r) { nrm += sr[r] * sr[r]; si[r] = 0.f; }
#pragma unroll
  for (int m = 1; m < 64; m <<= 1) nrm += shx(nrm, m);
  float inv = rsqrtf(nrm);
  inv = inv * (1.5f - 0.5f * nrm * inv * inv);
#pragma unroll
  for (int r = 0; r < 8; ++r) sr[r] *= inv;
  run_circuit(sr, si, gU, gCS);
  float p[8], P = 0.f;
#pragma unroll
  for (int r = 0; r < 8; ++r) { p[r] = sr[r] * sr[r] + si[r] * si[r]; P += p[r]; }
  float z[NQ];
#pragma unroll
  for (int q = 0; q < 6; ++q) z[q] = (lane & (32 >> q)) ? -P : P;
  z[6] = z[7] = z[8] = 0.f;
#pragma unroll
  for (int r = 0; r < 8; ++r) {
    z[6] += (r & 4) ? -p[r] : p[r];
    z[7] += (r & 2) ? -p[r] : p[r];
    z[8] += (r & 1) ? -p[r] : p[r];
  }
#pragma unroll
  for (int m = 1; m < 64; m <<= 1) {
#pragma unroll
    for (int q = 0; q < NQ; ++q) z[q] += shx(z[q], m);
  }
  int ffw = flags[1], ffb = flags[2];
  float lg[NCLS], mx = -1e30f;
#pragma unroll
  for (int k = 0; k < NCLS; ++k) {
    float t = ld(fcb, k, ffb);
#pragma unroll
    for (int q = 0; q < NQ; ++q) t += z[q] * ld(fcw, k * NQ + q, ffw);
    lg[k] = t; mx = fmaxf(mx, t);
  }
  float se = 0.f;
#pragma unroll
  for (int k = 0; k < NCLS; ++k) se += expf(lg[k] - mx);
  float lse = mx + logf(se);
  if (lane < NCLS) out[(size_t)wid * NCLS + lane] = lg[lane] - lse;
}

extern "C" void kernel_launch(void* const* d_in, const int* in_sizes, int n_in,
                              void* d_out, int out_size, void* d_ws, size_t ws_size,
                              hipStream_t stream) {
  const void* x   = d_in[0];
  const void* rot = d_in[1];
  const void* crx = d_in[2];
  const void* fcw = d_in[3];
  const void* fcb = d_in[4];
  float* out = (float*)d_out;
  if (ws_size >= WS_NEED) {
    __hip_bfloat16* A  = (__hip_bfloat16*)((char*)d_ws + A_OFF);
    __hip_bfloat16* BT = (__hip_bfloat16*)((char*)d_ws + BT_OFF);
    float*          Zp = (float*)((char*)d_ws + ZP_OFF);
    prep_kernel<<<DIM + (B_TOT * DIM) / (256 * 8), 256, 0, stream>>>(x, rot, crx, A, BT);
    gemm_z_kernel<<<(B_TOT / 128) * (1024 / 128), 256, 0, stream>>>(
        (const unsigned short*)A, (const unsigned short*)BT, Zp);
    zred_kernel<<<B_TOT / 256, 256, 0, stream>>>(Zp, fcw, fcb, out);
  } else {
    qnn_kernel<<<(B_TOT * 64) / 256, 256, 0, stream>>>(x, rot, crx, fcw, fcb, out);
  }
}

// Round 14
// 140.847 us; speedup vs baseline: 3.2499x; 1.0079x over previous
//
#include <hip/hip_runtime.h>
#include <hip/hip_bf16.h>
#include <math.h>

#define NQ 9
#define NL 10
#define DIM 512
#define NCLS 10
#define B_TOT 16384

// ws layout (bytes): A bf16 [16384x512] @ 0 (16MB); BT bf16 [1024x512] @ 16MB;
// Zp f32 [8][16384][10] @ 32MB (5.25MB).
// NOTE (R13 lesson): bulk data between workgroups of ONE launch is unsafe on
// CDNA4 (per-XCD L2 non-coherent; fences insufficient for plain stores) —
// Zp crosses a kernel boundary instead.
#define A_OFF   ((size_t)0)
#define BT_OFF  ((size_t)16 << 20)
#define ZP_OFF  ((size_t)32 << 20)
#define WS_NEED (((size_t)96) << 20)

__device__ __forceinline__ float shx(float v, int m) { return __shfl_xor(v, m, 64); }

__device__ __forceinline__ int looks_bf16(const void* p, int count) {
  const unsigned short* u = (const unsigned short*)p;
  int n = count < 64 ? count : 64;
  int good = 0;
  for (int i = 0; i < n; ++i) {
    unsigned short v = u[i];
    int e = (v >> 7) & 0xFF;
    good += (e >= 100 && e <= 140) || ((v & 0x7FFF) == 0);
  }
  return good * 8 >= n * 7;
}

__device__ __forceinline__ float ld(const void* p, int i, int isbf) {
  if (isbf) return __uint_as_float(((unsigned)((const unsigned short*)p)[i]) << 16);
  return ((const float*)p)[i];
}

// ---------------- 8-amp gate helpers (verified R3; used by fallback) -------
template<int M>
__device__ __forceinline__ void rot_x(float (&sr)[8], float (&si)[8], const float* u) {
  float4 uA = *(const float4*)u;
  float4 uB = *(const float4*)(u + 4);
  bool hi = (threadIdx.x & M) != 0;
  float ar = hi ? uB.z : uA.x, ai = hi ? uB.w : uA.y;
  float br = hi ? uB.x : uA.z, bi = hi ? uB.y : uA.w;
#pragma unroll
  for (int r = 0; r < 8; ++r) {
    float pr = shx(sr[r], M), pi = shx(si[r], M);
    float nr = ar * sr[r] - ai * si[r] + br * pr - bi * pi;
    float ni = ar * si[r] + ai * sr[r] + br * pi + bi * pr;
    sr[r] = nr; si[r] = ni;
  }
}
template<int S>
__device__ __forceinline__ void rot_r(float (&sr)[8], float (&si)[8], const float* u) {
  float4 uA = *(const float4*)u;
  float4 uB = *(const float4*)(u + 4);
#pragma unroll
  for (int r0 = 0; r0 < 8; ++r0) {
    if (r0 & S) continue;
    int r1 = r0 + S;
    float a0r = sr[r0], a0i = si[r0], a1r = sr[r1], a1i = si[r1];
    sr[r0] = uA.x * a0r - uA.y * a0i + uA.z * a1r - uA.w * a1i;
    si[r0] = uA.x * a0i + uA.y * a0r + uA.z * a1i + uA.w * a1r;
    sr[r1] = uB.x * a0r - uB.y * a0i + uB.z * a1r - uB.w * a1i;
    si[r1] = uB.x * a0i + uB.y * a0r + uB.z * a1i + uB.w * a1r;
  }
}
template<int MC, int MT>
__device__ __forceinline__ void crx_ll(float (&sr)[8], float (&si)[8], const float* cs) {
  bool ctrl = (threadIdx.x & MC) != 0;
  float c = ctrl ? cs[0] : 1.0f;
  float s = ctrl ? cs[1] : 0.0f;
#pragma unroll
  for (int r = 0; r < 8; ++r) {
    float pr = shx(sr[r], MT), pi = shx(si[r], MT);
    float nr = c * sr[r] + s * pi;
    float ni = c * si[r] - s * pr;
    sr[r] = nr; si[r] = ni;
  }
}
template<int MC, int ST>
__device__ __forceinline__ void crx_lr(float (&sr)[8], float (&si)[8], const float* cs) {
  bool ctrl = (threadIdx.x & MC) != 0;
  float c = ctrl ? cs[0] : 1.0f;
  float s = ctrl ? cs[1] : 0.0f;
#pragma unroll
  for (int r0 = 0; r0 < 8; ++r0) {
    if (r0 & ST) continue;
    int r1 = r0 + ST;
    float a0r = sr[r0], a0i = si[r0], a1r = sr[r1], a1i = si[r1];
    sr[r0] = c * a0r + s * a1i;  si[r0] = c * a0i - s * a1r;
    sr[r1] = c * a1r + s * a0i;  si[r1] = c * a1i - s * a0r;
  }
}
template<int PC, int ST>
__device__ __forceinline__ void crx_rr(float (&sr)[8], float (&si)[8], const float* cs) {
  float c = cs[0], s = cs[1];
#pragma unroll
  for (int r0 = 0; r0 < 8; ++r0) {
    if (r0 & ST) continue;
    if (!((r0 >> PC) & 1)) continue;
    int r1 = r0 + ST;
    float a0r = sr[r0], a0i = si[r0], a1r = sr[r1], a1i = si[r1];
    sr[r0] = c * a0r + s * a1i;  si[r0] = c * a0i - s * a1r;
    sr[r1] = c * a1r + s * a0i;  si[r1] = c * a1i - s * a0r;
  }
}
template<int PC, int MT>
__device__ __forceinline__ void crx_rl(float (&sr)[8], float (&si)[8], const float* cs) {
  float c = cs[0], s = cs[1];
#pragma unroll
  for (int r = 0; r < 8; ++r) {
    if (!((r >> PC) & 1)) continue;
    float pr = shx(sr[r], MT), pi = shx(si[r], MT);
    float nr = c * sr[r] + s * pi;
    float ni = c * si[r] - s * pr;
    sr[r] = nr; si[r] = ni;
  }
}

__device__ __forceinline__ void build_gates(const void* rot, const void* crx,
                                            float* gU, float* gCS) {
  int tid = threadIdx.x;
  __shared__ int gflags[2];
  if (tid == 0) {
    gflags[0] = looks_bf16(rot, NL * NQ * 3);
    gflags[1] = looks_bf16(crx, NL * NQ);
  }
  __syncthreads();
  if (tid < NL * NQ) {
    int frot = gflags[0], fcrx = gflags[1];
    float phi = ld(rot, tid * 3 + 0, frot);
    float th  = ld(rot, tid * 3 + 1, frot);
    float om  = ld(rot, tid * 3 + 2, frot);
    float c = cosf(0.5f * th), s = sinf(0.5f * th);
    float a = 0.5f * (phi + om), b = 0.5f * (phi - om);
    float ca = cosf(a), sa = sinf(a), cb = cosf(b), sb = sinf(b);
    float* u = gU + tid * 8;
    u[0] =  ca * c; u[1] = -sa * c;
    u[2] = -cb * s; u[3] = -sb * s;
    u[4] =  cb * s; u[5] = -sb * s;
    u[6] =  ca * c; u[7] =  sa * c;
    float t2 = 0.5f * ld(crx, tid, fcrx);
    gCS[tid * 2 + 0] = cosf(t2);
    gCS[tid * 2 + 1] = sinf(t2);
  }
  __syncthreads();
}

__device__ __forceinline__ void run_circuit(float (&sr)[8], float (&si)[8],
                                            const float* gU, const float* gCS) {
#pragma unroll 1
  for (int n = 0; n < NL; ++n) {
    const float* U  = gU  + n * NQ * 8;
    const float* CS = gCS + n * NQ * 2;
    rot_x<32>(sr, si, U + 0 * 8);
    rot_x<16>(sr, si, U + 1 * 8);
    rot_x< 8>(sr, si, U + 2 * 8);
    rot_x< 4>(sr, si, U + 3 * 8);
    rot_x< 2>(sr, si, U + 4 * 8);
    rot_x< 1>(sr, si, U + 5 * 8);
    rot_r< 4>(sr, si, U + 6 * 8);
    rot_r< 2>(sr, si, U + 7 * 8);
    rot_r< 1>(sr, si, U + 8 * 8);
    crx_ll<32, 16>(sr, si, CS + 0 * 2);
    crx_ll<16,  8>(sr, si, CS + 1 * 2);
    crx_ll< 8,  4>(sr, si, CS + 2 * 2);
    crx_ll< 4,  2>(sr, si, CS + 3 * 2);
    crx_ll< 2,  1>(sr, si, CS + 4 * 2);
    crx_lr< 1,  4>(sr, si, CS + 5 * 2);
    crx_rr< 2,  2>(sr, si, CS + 6 * 2);
    crx_rr< 1,  1>(sr, si, CS + 7 * 2);
    crx_rl< 0, 32>(sr, si, CS + 8 * 2);
  }
}

// ---------------- 2-amp gate helpers (4-wave-per-column wbuild) ------------
template<int M>
__device__ __forceinline__ void rot_lane2(float (&sr)[2], float (&si)[2], const float* u) {
  float4 uA = *(const float4*)u;
  float4 uB = *(const float4*)(u + 4);
  bool hi = (threadIdx.x & M) != 0;
  float ar = hi ? uB.z : uA.x, ai = hi ? uB.w : uA.y;
  float br = hi ? uB.x : uA.z, bi = hi ? uB.y : uA.w;
#pragma unroll
  for (int r = 0; r < 2; ++r) {
    float pr = shx(sr[r], M), pi = shx(si[r], M);
    float nr = ar * sr[r] - ai * si[r] + br * pr - bi * pi;
    float ni = ar * si[r] + ai * sr[r] + br * pi + bi * pr;
    sr[r] = nr; si[r] = ni;
  }
}
__device__ __forceinline__ void rot_reg2(float (&sr)[2], float (&si)[2], const float* u) {
  float4 uA = *(const float4*)u;
  float4 uB = *(const float4*)(u + 4);
  float a0r = sr[0], a0i = si[0], a1r = sr[1], a1i = si[1];
  sr[0] = uA.x * a0r - uA.y * a0i + uA.z * a1r - uA.w * a1i;
  si[0] = uA.x * a0i + uA.y * a0r + uA.z * a1i + uA.w * a1r;
  sr[1] = uB.x * a0r - uB.y * a0i + uB.z * a1r - uB.w * a1i;
  si[1] = uB.x * a0i + uB.y * a0r + uB.z * a1i + uB.w * a1r;
}
__device__ __forceinline__ void crx_lane2(float (&sr)[2], float (&si)[2],
                                          float c, float s, int MT) {
#pragma unroll
  for (int r = 0; r < 2; ++r) {
    float pr = shx(sr[r], MT), pi = shx(si[r], MT);
    float nr = c * sr[r] + s * pi;
    float ni = c * si[r] - s * pr;
    sr[r] = nr; si[r] = ni;
  }
}
__device__ __forceinline__ void crx_reg2(float (&sr)[2], float (&si)[2], float c, float s) {
  float a0r = sr[0], a0i = si[0], a1r = sr[1], a1i = si[1];
  sr[0] = c * a0r + s * a1i;  si[0] = c * a0i - s * a1r;
  sr[1] = c * a1r + s * a0i;  si[1] = c * a1i - s * a0r;
}

// -------- fused prep: blocks 0..511 build one W column each (4 waves/col),
// -------- blocks 512.. cast x->bf16 and fill remaining SIMDs ---------------
// Barrier reduction (verified bit-identical, R13 first-launch): layer n's
// CRX(8->0) is fused into layer (n+1)'s Rot(q0)xRot(q1) LDS round-trip
// -> 2 round-trips/layer + 1 final (44 barriers vs 60).
__global__ __launch_bounds__(256) void prep_kernel(const void* __restrict__ x,
                                                   const void* __restrict__ rot,
                                                   const void* __restrict__ crx,
                                                   __hip_bfloat16* __restrict__ A,
                                                   __hip_bfloat16* __restrict__ BT) {
  int tid = threadIdx.x;
  if (blockIdx.x < DIM) {
    __shared__ __align__(16) float gU[NL * NQ * 8];
    __shared__ __align__(16) float gCS[NL * NQ * 2];
    __shared__ float sRe[DIM], sIm[DIM];
    build_gates(rot, crx, gU, gCS);
    int lane = tid & 63, wv = tid >> 6;
    int idx0 = wv * 128 + lane * 2;
    int k = blockIdx.x;
    float sr[2], si[2];
    sr[0] = (idx0 == k) ? 1.f : 0.f;
    sr[1] = (idx0 + 1 == k) ? 1.f : 0.f;
    si[0] = si[1] = 0.f;
#pragma unroll 1
    for (int n = 0; n < NL; ++n) {
      const float* U   = gU  + n * NQ * 8;
      const float* CS  = gCS + n * NQ * 2;
      const float* CSp = gCS + (n - 1) * NQ * 2;  // valid only for n>0
      // --- fused RT: [CRX(8->0) of layer n-1] + Rot(q0)xRot(q1) of layer n
      __syncthreads();
      sRe[idx0] = sr[0]; sIm[idx0] = si[0];
      sRe[idx0 + 1] = sr[1]; sIm[idx0 + 1] = si[1];
      __syncthreads();
      {
        const float* U0 = U; const float* U1 = U + 8;
        int a = wv >> 1, b = wv & 1;
        float mr[4], mi[4];
#pragma unroll
        for (int w2 = 0; w2 < 4; ++w2) {
          int a2 = w2 >> 1, b2 = w2 & 1;
          float u0r = U0[(a * 2 + a2) * 2], u0i = U0[(a * 2 + a2) * 2 + 1];
          float u1r = U1[(b * 2 + b2) * 2], u1i = U1[(b * 2 + b2) * 2 + 1];
          mr[w2] = u0r * u1r - u0i * u1i;
          mi[w2] = u0r * u1i + u0i * u1r;
        }
        float x0r[4], x0i[4], v1r[4], v1i[4];
#pragma unroll
        for (int w2 = 0; w2 < 4; ++w2) {
          x0r[w2] = sRe[w2 * 128 + lane * 2 + 0];
          x0i[w2] = sIm[w2 * 128 + lane * 2 + 0];
          v1r[w2] = sRe[w2 * 128 + lane * 2 + 1];
          v1i[w2] = sIm[w2 * 128 + lane * 2 + 1];
        }
        float x1r[4], x1i[4];
        if (n > 0) {
          float cp = CSp[16], sp = CSp[17];
#pragma unroll
          for (int w2 = 0; w2 < 4; ++w2) {
            x1r[w2] = cp * v1r[w2] + sp * v1i[w2 ^ 2];
            x1i[w2] = cp * v1i[w2] - sp * v1r[w2 ^ 2];
          }
        } else {
#pragma unroll
          for (int w2 = 0; w2 < 4; ++w2) { x1r[w2] = v1r[w2]; x1i[w2] = v1i[w2]; }
        }
        float nr0 = 0.f, ni0 = 0.f, nr1 = 0.f, ni1 = 0.f;
#pragma unroll
        for (int w2 = 0; w2 < 4; ++w2) {
          nr0 += mr[w2] * x0r[w2] - mi[w2] * x0i[w2];
          ni0 += mr[w2] * x0i[w2] + mi[w2] * x0r[w2];
          nr1 += mr[w2] * x1r[w2] - mi[w2] * x1i[w2];
          ni1 += mr[w2] * x1i[w2] + mi[w2] * x1r[w2];
        }
        sr[0] = nr0; si[0] = ni0; sr[1] = nr1; si[1] = ni1;
      }
      // --- Rot q2..q7 (lane), q8 (reg) ---
      rot_lane2<32>(sr, si, U + 2 * 8);
      rot_lane2<16>(sr, si, U + 3 * 8);
      rot_lane2< 8>(sr, si, U + 4 * 8);
      rot_lane2< 4>(sr, si, U + 5 * 8);
      rot_lane2< 2>(sr, si, U + 6 * 8);
      rot_lane2< 1>(sr, si, U + 7 * 8);
      rot_reg2(sr, si, U + 8 * 8);
      // --- CRX(0->1): ctrl wv bit1, target wv bit0 (cross-wave) ---
      __syncthreads();
      sRe[idx0] = sr[0]; sIm[idx0] = si[0];
      sRe[idx0 + 1] = sr[1]; sIm[idx0 + 1] = si[1];
      __syncthreads();
      {
        float c = (wv & 2) ? CS[0] : 1.f, s = (wv & 2) ? CS[1] : 0.f;
        int p0 = (wv ^ 1) * 128 + lane * 2;
#pragma unroll
        for (int r = 0; r < 2; ++r) {
          float pr = sRe[p0 + r], pi = sIm[p0 + r];
          float nr = c * sr[r] + s * pi;
          float ni = c * si[r] - s * pr;
          sr[r] = nr; si[r] = ni;
        }
      }
      { float c = (wv & 1) ? CS[2] : 1.f, s = (wv & 1) ? CS[3] : 0.f;
        crx_lane2(sr, si, c, s, 32); }
      { bool ct = (lane & 32); crx_lane2(sr, si, ct ? CS[4] : 1.f, ct ? CS[5] : 0.f, 16); }
      { bool ct = (lane & 16); crx_lane2(sr, si, ct ? CS[6] : 1.f, ct ? CS[7] : 0.f, 8); }
      { bool ct = (lane &  8); crx_lane2(sr, si, ct ? CS[8] : 1.f, ct ? CS[9] : 0.f, 4); }
      { bool ct = (lane &  4); crx_lane2(sr, si, ct ? CS[10] : 1.f, ct ? CS[11] : 0.f, 2); }
      { bool ct = (lane &  2); crx_lane2(sr, si, ct ? CS[12] : 1.f, ct ? CS[13] : 0.f, 1); }
      { bool ct = (lane & 1); crx_reg2(sr, si, ct ? CS[14] : 1.f, ct ? CS[15] : 0.f); }
      // CRX(8->0) of this layer is applied in the next iteration's fused RT
      // (or the final RT below for the last layer).
    }
    // final CRX(8->0) for layer NL-1
    __syncthreads();
    sRe[idx0] = sr[0]; sIm[idx0] = si[0];
    sRe[idx0 + 1] = sr[1]; sIm[idx0 + 1] = si[1];
    __syncthreads();
    {
      const float* CS9 = gCS + (NL - 1) * NQ * 2;
      float c = CS9[16], s = CS9[17];
      int p1 = (wv ^ 2) * 128 + lane * 2 + 1;
      float pr = sRe[p1], pi = sIm[p1];
      float nr = c * sr[1] + s * pi;
      float ni = c * si[1] - s * pr;
      sr[1] = nr; si[1] = ni;
    }
#pragma unroll
    for (int r = 0; r < 2; ++r) {
      int j = idx0 + r;
      BT[(size_t)j * DIM + k]         = __float2bfloat16(sr[r]);  // Re W[j,k]
      BT[(size_t)(DIM + j) * DIM + k] = __float2bfloat16(si[r]);  // Im W[j,k]
    }
  } else {
    __shared__ int fx;
    if (tid == 0) fx = looks_bf16(x, B_TOT * DIM);
    __syncthreads();
    size_t i0 = ((size_t)(blockIdx.x - DIM) * 256 + tid) * 8;
    if (fx) {
      *(uint4*)(A + i0) = *(const uint4*)((const unsigned short*)x + i0);
    } else {
      const float4* src = (const float4*)((const float*)x + i0);
      float4 a = src[0], b = src[1];
      __hip_bfloat16 o[8];
      o[0] = __float2bfloat16(a.x); o[1] = __float2bfloat16(a.y);
      o[2] = __float2bfloat16(a.z); o[3] = __float2bfloat16(a.w);
      o[4] = __float2bfloat16(b.x); o[5] = __float2bfloat16(b.y);
      o[6] = __float2bfloat16(b.z); o[7] = __float2bfloat16(b.w);
      *(uint4*)(A + i0) = *(uint4*)o;
    }
  }
}

// ------- GEMM (BK=64) + MFMA-based z-reduction: Zp[panel][m][q], no C ------
// All acc[][] indexing fully unrolled (R9 scratch-spill lesson).
using frag8 = __attribute__((ext_vector_type(8))) short;
using frag4 = __attribute__((ext_vector_type(4))) float;

typedef __attribute__((address_space(1))) const unsigned int GU32;
typedef __attribute__((address_space(3))) unsigned int LU32;
__device__ __forceinline__ void async16(const void* g, void* l) {
  __builtin_amdgcn_global_load_lds((GU32*)g, (LU32*)l, 16, 0, 0);
}

#define PPITCH 136  // pA/ST row pitch in bf16 (128 + 8 pad)
#define PANEL (128 * 32)

__global__ __launch_bounds__(256) void gemm_z_kernel(const unsigned short* __restrict__ A,
                                                     const unsigned short* __restrict__ BT,
                                                     float* __restrict__ Zp) {
  __shared__ __align__(16) unsigned short lsm[128 * PPITCH + 16 * PPITCH];
  unsigned short* lA0 = lsm;
  unsigned short* lA1 = lsm + PANEL;
  unsigned short* lB0 = lsm + 2 * PANEL;
  unsigned short* lB1 = lsm + 3 * PANEL;
  unsigned short* pA  = lsm;
  unsigned short* STm = lsm + 128 * PPITCH;
  int bid = blockIdx.x;
  int xcd = bid & 7;
  int slot = bid >> 3;
  int n0 = (slot & 7) * 128;
  int m0 = (xcd * 16 + (slot >> 3)) * 128;
  int tid = threadIdx.x;
  int wv = tid >> 6, lane = tid & 63;
  int wm = wv >> 1, wn = wv & 1;
  int row = lane & 15, quad = lane >> 4;
  // build sign matrix ST[q][k2] (disjoint from staging)
  for (int i = tid; i < 16 * 128; i += 256) {
    int q = i >> 7, k2 = i & 127;
    int j = (n0 + k2) & 511;
    float sg = (q < 9) ? (((j >> (8 - q)) & 1) ? -1.f : 1.f) : (q == 9 ? 1.f : 0.f);
    __hip_bfloat16 h = __float2bfloat16(sg);
    STm[q * PPITCH + k2] = *(unsigned short*)&h;
  }
  int srow = wv * 32 + (lane >> 2);
  int scol = (lane & 3) * 8;
  const unsigned short* gA = A + (size_t)(m0 + srow) * 512 + scol;
  const unsigned short* gB = BT + (size_t)(n0 + srow) * 512 + scol;
  frag4 acc[4][4] = {};
#pragma unroll 1
  for (int k0 = 0; k0 < 512; k0 += 64) {
    __syncthreads();
    async16(gA + k0,                 &lA0[(wv * 32) * 32]);
    async16(gA + k0 + 16 * 512,      &lA0[(wv * 32 + 16) * 32]);
    async16(gA + k0 + 32,            &lA1[(wv * 32) * 32]);
    async16(gA + k0 + 32 + 16 * 512, &lA1[(wv * 32 + 16) * 32]);
    async16(gB + k0,                 &lB0[(wv * 32) * 32]);
    async16(gB + k0 + 16 * 512,      &lB0[(wv * 32 + 16) * 32]);
    async16(gB + k0 + 32,            &lB1[(wv * 32) * 32]);
    async16(gB + k0 + 32 + 16 * 512, &lB1[(wv * 32 + 16) * 32]);
    __syncthreads();
    {
      frag8 af[4], bf[4];
#pragma unroll
      for (int i = 0; i < 4; ++i) {
        af[i] = *(const frag8*)(&lA0[(wm * 64 + i * 16 + row) * 32 + quad * 8]);
        bf[i] = *(const frag8*)(&lB0[(wn * 64 + i * 16 + row) * 32 + quad * 8]);
      }
#pragma unroll
      for (int mi = 0; mi < 4; ++mi)
#pragma unroll
        for (int ni = 0; ni < 4; ++ni)
          acc[mi][ni] = __builtin_amdgcn_mfma_f32_16x16x32_bf16(af[mi], bf[ni],
                                                                acc[mi][ni], 0, 0, 0);
    }
    {
      frag8 af[4], bf[4];
#pragma unroll
      for (int i = 0; i < 4; ++i) {
        af[i] = *(const frag8*)(&lA1[(wm * 64 + i * 16 + row) * 32 + quad * 8]);
        bf[i] = *(const frag8*)(&lB1[(wn * 64 + i * 16 + row) * 32 + quad * 8]);
      }
#pragma unroll
      for (int mi = 0; mi < 4; ++mi)
#pragma unroll
        for (int ni = 0; ni < 4; ++ni)
          acc[mi][ni] = __builtin_amdgcn_mfma_f32_16x16x32_bf16(af[mi], bf[ni],
                                                                acc[mi][ni], 0, 0, 0);
    }
  }
  // ---- epilogue: P = acc^2 -> LDS bf16 (A-operand layout) -----------------
  __syncthreads();
#pragma unroll
  for (int mi = 0; mi < 4; ++mi)
#pragma unroll
    for (int ni = 0; ni < 4; ++ni)
#pragma unroll
      for (int rg = 0; rg < 4; ++rg) {
        float v = acc[mi][ni][rg];
        float p = v * v;
        int mrow = wm * 64 + mi * 16 + quad * 4 + rg;
        int k2 = wn * 64 + ni * 16 + row;
        __hip_bfloat16 h = __float2bfloat16(p);
        pA[mrow * PPITCH + k2] = *(unsigned short*)&h;
      }
  __syncthreads();
  // ---- second GEMM: Ztile = P . ST^T (8 m-tiles; wave wv does wv, wv+4) ---
  frag8 b2[4];
#pragma unroll
  for (int kk = 0; kk < 4; ++kk)
    b2[kk] = *(const frag8*)(&STm[row * PPITCH + kk * 32 + quad * 8]);
  frag4 zacc2[2] = {};
#pragma unroll
  for (int t = 0; t < 2; ++t) {
    int mt = wv + t * 4;
#pragma unroll
    for (int kk = 0; kk < 4; ++kk) {
      frag8 a2 = *(const frag8*)(&pA[(mt * 16 + row) * PPITCH + kk * 32 + quad * 8]);
      zacc2[t] = __builtin_amdgcn_mfma_f32_16x16x32_bf16(a2, b2[kk], zacc2[t], 0, 0, 0);
    }
  }
  int panel = n0 >> 7;
  if (row < 10) {
#pragma unroll
    for (int t = 0; t < 2; ++t) {
      int mt = wv + t * 4;
#pragma unroll
      for (int rg = 0; rg < 4; ++rg) {
        int mrow = m0 + mt * 16 + quad * 4 + rg;
        Zp[(size_t)panel * (B_TOT * 10) + (size_t)mrow * 10 + row] = zacc2[t][rg];
      }
    }
  }
}

// ------- final reduction: sum 8 panels, normalize, logits, log_softmax -----
__global__ __launch_bounds__(256) void zred_kernel(const float* __restrict__ Zp,
                                                   const void* __restrict__ fcw,
                                                   const void* __restrict__ fcb,
                                                   float* __restrict__ out) {
  __shared__ int flags[2];
  __shared__ float sW[NCLS * NQ];
  __shared__ float sB[NCLS];
  int tid = threadIdx.x;
  if (tid == 0) {
    flags[0] = looks_bf16(fcw, NCLS * NQ);
    flags[1] = looks_bf16(fcb, NCLS);
  }
  __syncthreads();
  if (tid < NCLS * NQ) sW[tid] = ld(fcw, tid, flags[0]);
  if (tid < NCLS)      sB[tid] = ld(fcb, tid, flags[1]);
  __syncthreads();
  int row = blockIdx.x * 256 + tid;
  float z[10];
#pragma unroll
  for (int q = 0; q < 10; ++q) z[q] = 0.f;
#pragma unroll
  for (int pnl = 0; pnl < 8; ++pnl) {
    const float* p = Zp + (size_t)pnl * (B_TOT * 10) + (size_t)row * 10;
#pragma unroll
    for (int q = 0; q < 10; ++q) z[q] += p[q];
  }
  float invP = 1.0f / z[9];
#pragma unroll
  for (int q = 0; q < NQ; ++q) z[q] *= invP;
  float lg[NCLS], mx = -1e30f;
#pragma unroll
  for (int k = 0; k < NCLS; ++k) {
    float t = sB[k];
#pragma unroll
    for (int q = 0; q < NQ; ++q) t += z[q] * sW[k * NQ + q];
    lg[k] = t; mx = fmaxf(mx, t);
  }
  float se = 0.f;
#pragma unroll
  for (int k = 0; k < NCLS; ++k) se += expf(lg[k] - mx);
  float lse = mx + logf(se);
#pragma unroll
  for (int k = 0; k < NCLS; ++k) out[(size_t)row * NCLS + k] = lg[k] - lse;
}

// ---------------- fallback: round-3 passing monolithic kernel --------------
__global__ __launch_bounds__(256) void qnn_kernel(
    const void* __restrict__ x, const void* __restrict__ rot,
    const void* __restrict__ crx, const void* __restrict__ fcw,
    const void* __restrict__ fcb, float* __restrict__ out) {
  __shared__ __align__(16) float gU[NL * NQ * 8];
  __shared__ __align__(16) float gCS[NL * NQ * 2];
  __shared__ int flags[3];
  int tid = threadIdx.x;
  if (tid == 0) {
    flags[0] = looks_bf16(x, B_TOT * DIM);
    flags[1] = looks_bf16(fcw, NCLS * NQ);
    flags[2] = looks_bf16(fcb, NCLS);
  }
  build_gates(rot, crx, gU, gCS);
  __syncthreads();
  int wid = (blockIdx.x * blockDim.x + tid) >> 6;
  int lane = tid & 63;
  float sr[8], si[8];
  if (flags[0]) {
    const uint4 u = *(const uint4*)((const unsigned short*)x + (size_t)wid * DIM + lane * 8);
    sr[0] = __uint_as_float(u.x << 16); sr[1] = __uint_as_float(u.x & 0xffff0000u);
    sr[2] = __uint_as_float(u.y << 16); sr[3] = __uint_as_float(u.y & 0xffff0000u);
    sr[4] = __uint_as_float(u.z << 16); sr[5] = __uint_as_float(u.z & 0xffff0000u);
    sr[6] = __uint_as_float(u.w << 16); sr[7] = __uint_as_float(u.w & 0xffff0000u);
  } else {
    const float4* xf = (const float4*)((const float*)x + (size_t)wid * DIM) + lane * 2;
    float4 a = xf[0], b = xf[1];
    sr[0] = a.x; sr[1] = a.y; sr[2] = a.z; sr[3] = a.w;
    sr[4] = b.x; sr[5] = b.y; sr[6] = b.z; sr[7] = b.w;
  }
  float nrm = 0.f;
#pragma unroll
  for (int r = 0; r < 8; ++r) { nrm += sr[r] * sr[r]; si[r] = 0.f; }
#pragma unroll
  for (int m = 1; m < 64; m <<= 1) nrm += shx(nrm, m);
  float inv = rsqrtf(nrm);
  inv = inv * (1.5f - 0.5f * nrm * inv * inv);
#pragma unroll
  for (int r = 0; r < 8; ++r) sr[r] *= inv;
  run_circuit(sr, si, gU, gCS);
  float p[8], P = 0.f;
#pragma unroll
  for (int r = 0; r < 8; ++r) { p[r] = sr[r] * sr[r] + si[r] * si[r]; P += p[r]; }
  float z[NQ];
#pragma unroll
  for (int q = 0; q < 6; ++q) z[q] = (lane & (32 >> q)) ? -P : P;
  z[6] = z[7] = z[8] = 0.f;
#pragma unroll
  for (int r = 0; r < 8; ++r) {
    z[6] += (r & 4) ? -p[r] : p[r];
    z[7] += (r & 2) ? -p[r] : p[r];
    z[8] += (r & 1) ? -p[r] : p[r];
  }
#pragma unroll
  for (int m = 1; m < 64; m <<= 1) {
#pragma unroll
    for (int q = 0; q < NQ; ++q) z[q] += shx(z[q], m);
  }
  int ffw = flags[1], ffb = flags[2];
  float lg[NCLS], mx = -1e30f;
#pragma unroll
  for (int k = 0; k < NCLS; ++k) {
    float t = ld(fcb, k, ffb);
#pragma unroll
    for (int q = 0; q < NQ; ++q) t += z[q] * ld(fcw, k * NQ + q, ffw);
    lg[k] = t; mx = fmaxf(mx, t);
  }
  float se = 0.f;
#pragma unroll
  for (int k = 0; k < NCLS; ++k) se += expf(lg[k] - mx);
  float lse = mx + logf(se);
  if (lane < NCLS) out[(size_t)wid * NCLS + lane] = lg[lane] - lse;
}

extern "C" void kernel_launch(void* const* d_in, const int* in_sizes, int n_in,
                              void* d_out, int out_size, void* d_ws, size_t ws_size,
                              hipStream_t stream) {
  const void* x   = d_in[0];
  const void* rot = d_in[1];
  const void* crx = d_in[2];
  const void* fcw = d_in[3];
  const void* fcb = d_in[4];
  float* out = (float*)d_out;
  if (ws_size >= WS_NEED) {
    __hip_bfloat16* A  = (__hip_bfloat16*)((char*)d_ws + A_OFF);
    __hip_bfloat16* BT = (__hip_bfloat16*)((char*)d_ws + BT_OFF);
    float*          Zp = (float*)((char*)d_ws + ZP_OFF);
    prep_kernel<<<DIM + (B_TOT * DIM) / (256 * 8), 256, 0, stream>>>(x, rot, crx, A, BT);
    gemm_z_kernel<<<(B_TOT / 128) * (1024 / 128), 256, 0, stream>>>(
        (const unsigned short*)A, (const unsigned short*)BT, Zp);
    zred_kernel<<<B_TOT / 256, 256, 0, stream>>>(Zp, fcw, fcb, out);
  } else {
    qnn_kernel<<<(B_TOT * 64) / 256, 256, 0, stream>>>(x, rot, crx, fcw, fcb, out);
  }
}